// Round 1
// baseline (692.341 us; speedup 1.0000x reference)
//
#include <hip/hip_runtime.h>

// GCN link predictor, MI355X.
// Pipeline per call (all on `stream`, graph-capture safe):
//   memset cnt -> hist -> scan(3 kernels) -> csr fill
//   gemm1(x@W1) -> agg(relu) -> gemm2 -> agg(relu) -> gemm3 -> agg -> fused MLP
// Workspace layout: bufA(51.2M) bufB(51.2M) csr(12.8M) cnt/isq/rs/cur/bsum (~1.7M)

// ---------------- CSR build ----------------

__global__ void k_hist(const int* __restrict__ ei, int E, int* __restrict__ cnt) {
  int e = blockIdx.x * 256 + threadIdx.x;
  if (e < E) atomicAdd(&cnt[ei[E + e]], 1);  // dst row of edge_index
}

__global__ void k_scan1(const int* __restrict__ cnt, int* __restrict__ bsum, int n) {
  __shared__ int s[256];
  int i = blockIdx.x * 256 + threadIdx.x;
  int t = threadIdx.x;
  s[t] = (i < n) ? cnt[i] : 0;
  __syncthreads();
  for (int d = 128; d > 0; d >>= 1) {
    if (t < d) s[t] += s[t + d];
    __syncthreads();
  }
  if (t == 0) bsum[blockIdx.x] = s[0];
}

// single block scans the (<=512) block sums; writes exclusive sums in place,
// total edge count to rs[n].
__global__ void k_scan2(int* __restrict__ bsum, int m, int* __restrict__ rs, int n) {
  __shared__ int s[512];
  int t = threadIdx.x;
  s[t] = (t < m) ? bsum[t] : 0;
  __syncthreads();
  for (int d = 1; d < 512; d <<= 1) {
    int v = (t >= d) ? s[t - d] : 0;
    __syncthreads();
    s[t] += v;
    __syncthreads();
  }
  if (t < m) bsum[t] = t ? s[t - 1] : 0;
  if (t == m - 1) rs[n] = s[t];
}

__global__ void k_scan3(const int* __restrict__ cnt, const int* __restrict__ bsum,
                        int* __restrict__ rs, int* __restrict__ cur,
                        float* __restrict__ isq, int n) {
  __shared__ int s[256];
  int i = blockIdx.x * 256 + threadIdx.x;
  int t = threadIdx.x;
  int v = (i < n) ? cnt[i] : 0;
  s[t] = v;
  __syncthreads();
  for (int d = 1; d < 256; d <<= 1) {
    int u = (t >= d) ? s[t - d] : 0;
    __syncthreads();
    s[t] += u;
    __syncthreads();
  }
  if (i < n) {
    int excl = bsum[blockIdx.x] + s[t] - v;   // exclusive prefix
    rs[i] = excl;
    cur[i] = excl;
    isq[i] = rsqrtf((float)(v + 1));          // deg includes self-loop
  }
}

__global__ void k_fill(const int* __restrict__ ei, int E, int* __restrict__ cur,
                       const float* __restrict__ isq, int2* __restrict__ csr) {
  int e = blockIdx.x * 256 + threadIdx.x;
  if (e < E) {
    int s = ei[e], d = ei[E + e];
    int pos = atomicAdd(&cur[d], 1);
    csr[pos] = make_int2(s, __float_as_int(isq[s]));  // (src, isq[src]) packed 8B
  }
}

// ---------------- dense GEMM: out[n,C] = A[n,K] @ W[K,C] ----------------
// 64-row tiles, W fully LDS-resident, A tile LDS (+4 float pad -> 2-way banks),
// 16x16 thread grid, 4 rows x (C/16) cols per thread. f32 vector FMA.

template <int K, int C>
__global__ __launch_bounds__(256) void k_gemm(const float* __restrict__ A,
                                              const float* __restrict__ W,
                                              float* __restrict__ out, int n) {
  constexpr int TM = 4, TN = C / 16, LDA = K + 4;
  __shared__ float Wl[K * C];
  __shared__ float Al[64 * LDA];
  int t = threadIdx.x;
  for (int i = t; i < K * C / 4; i += 256)
    ((float4*)Wl)[i] = ((const float4*)W)[i];
  int rowbase = blockIdx.x * 64;
  for (int idx = t; idx < 64 * (K / 4); idx += 256) {
    int r = idx / (K / 4), c4 = idx % (K / 4);
    int row = rowbase + r;
    float4 v = (row < n) ? ((const float4*)(A + (size_t)row * K))[c4]
                         : make_float4(0.f, 0.f, 0.f, 0.f);
    *(float4*)&Al[r * LDA + 4 * c4] = v;
  }
  __syncthreads();
  int tx = t & 15, ty = t >> 4;
  float acc[TM][TN] = {};
  for (int k = 0; k < K; ++k) {
    float a[TM];
#pragma unroll
    for (int i = 0; i < TM; ++i) a[i] = Al[(ty * TM + i) * LDA + k];
#pragma unroll
    for (int j = 0; j < TN; j += 4) {
      float4 w = *(const float4*)&Wl[k * C + tx * TN + j];
#pragma unroll
      for (int i = 0; i < TM; ++i) {
        acc[i][j + 0] += a[i] * w.x;
        acc[i][j + 1] += a[i] * w.y;
        acc[i][j + 2] += a[i] * w.z;
        acc[i][j + 3] += a[i] * w.w;
      }
    }
  }
#pragma unroll
  for (int i = 0; i < TM; ++i) {
    int row = rowbase + ty * TM + i;
    if (row < n) {
#pragma unroll
      for (int j = 0; j < TN; j += 4) {
        float4 v = make_float4(acc[i][j], acc[i][j + 1], acc[i][j + 2], acc[i][j + 3]);
        *(float4*)&out[(size_t)row * C + tx * TN + j] = v;
      }
    }
  }
}

// ---------------- CSR pull aggregation ----------------
// One wave per destination node; lane = channel (x2 for C=128).
// out[i] = isq[i]*(sum_e isq[src]*xw[src] + isq[i]*xw[i]) + b  (+relu)

template <int C, bool RELU>
__global__ __launch_bounds__(256) void k_agg(const float* __restrict__ xw,
                                             const int* __restrict__ rs,
                                             const int2* __restrict__ csr,
                                             const float* __restrict__ isq,
                                             const float* __restrict__ bias,
                                             float* __restrict__ out, int n) {
  int gw = (int)((blockIdx.x * blockDim.x + threadIdx.x) >> 6);
  int lane = threadIdx.x & 63;
  if (gw >= n) return;
  int e0 = rs[gw], e1 = rs[gw + 1];
  if (C == 128) {
    float acc0 = 0.f, acc1 = 0.f;
    int e = e0;
    for (; e + 1 < e1; e += 2) {  // unroll 2 for MLP
      int2 a = csr[e], b = csr[e + 1];
      float2 va = *(const float2*)&xw[(size_t)a.x * 128 + 2 * lane];
      float2 vb = *(const float2*)&xw[(size_t)b.x * 128 + 2 * lane];
      float wa = __int_as_float(a.y), wb = __int_as_float(b.y);
      acc0 += wa * va.x + wb * vb.x;
      acc1 += wa * va.y + wb * vb.y;
    }
    if (e < e1) {
      int2 a = csr[e];
      float2 va = *(const float2*)&xw[(size_t)a.x * 128 + 2 * lane];
      float wa = __int_as_float(a.y);
      acc0 += wa * va.x;
      acc1 += wa * va.y;
    }
    float qi = isq[gw];
    float2 self = *(const float2*)&xw[(size_t)gw * 128 + 2 * lane];
    float r0 = qi * (acc0 + qi * self.x) + bias[2 * lane];
    float r1 = qi * (acc1 + qi * self.y) + bias[2 * lane + 1];
    if (RELU) { r0 = fmaxf(r0, 0.f); r1 = fmaxf(r1, 0.f); }
    *(float2*)&out[(size_t)gw * 128 + 2 * lane] = make_float2(r0, r1);
  } else {
    float acc = 0.f;
    int e = e0;
    for (; e + 1 < e1; e += 2) {
      int2 a = csr[e], b = csr[e + 1];
      float va = xw[(size_t)a.x * C + lane];
      float vb = xw[(size_t)b.x * C + lane];
      acc += __int_as_float(a.y) * va + __int_as_float(b.y) * vb;
    }
    if (e < e1) {
      int2 a = csr[e];
      acc += __int_as_float(a.y) * xw[(size_t)a.x * C + lane];
    }
    float qi = isq[gw];
    float self = xw[(size_t)gw * C + lane];
    float r = qi * (acc + qi * self) + bias[lane];
    if (RELU) r = fmaxf(r, 0.f);
    out[(size_t)gw * C + lane] = r;
  }
}

// ---------------- fused link MLP ----------------
// pairs tile (64 rows x 128) gathered into LDS from z[s],z[d];
// h = relu(pairs@Wl1+bl1) in registers; logits = h@Wl2+bl2 via shfl_xor reduce.

__global__ __launch_bounds__(256) void k_mlp(const float* __restrict__ z,
                                             const int* __restrict__ eli, int nlab,
                                             const float* __restrict__ Wl1,
                                             const float* __restrict__ bl1,
                                             const float* __restrict__ Wl2,
                                             const float* __restrict__ bl2,
                                             float* __restrict__ out) {
  constexpr int K = 128, TM = 4, LDA = K + 4;
  __shared__ float Wl[K * 64];
  __shared__ float Al[64 * LDA];
  int t = threadIdx.x;
  for (int i = t; i < K * 64 / 4; i += 256)
    ((float4*)Wl)[i] = ((const float4*)Wl1)[i];
  int rowbase = blockIdx.x * 64;
  {
    int r = t >> 2, p = t & 3;  // 4 threads per row; p<2 -> z[s], p>=2 -> z[d]
    int row = rowbase + r;
    int idx = 0;
    if (row < nlab) idx = (p < 2) ? eli[row] : eli[nlab + row];
    const float4* src = (const float4*)(z + (size_t)idx * 64);
    int srcq = (p & 1) * 8;
    int dst = r * LDA + (p >= 2 ? 64 : 0) + (p & 1) * 32;
#pragma unroll
    for (int q = 0; q < 8; ++q)
      *(float4*)&Al[dst + 4 * q] = src[srcq + q];
  }
  __syncthreads();
  int tx = t & 15, ty = t >> 4;
  float acc[TM][4] = {};
  for (int k = 0; k < K; ++k) {
    float a[TM];
#pragma unroll
    for (int i = 0; i < TM; ++i) a[i] = Al[(ty * TM + i) * LDA + k];
    float4 w = *(const float4*)&Wl[k * 64 + tx * 4];
#pragma unroll
    for (int i = 0; i < TM; ++i) {
      acc[i][0] += a[i] * w.x;
      acc[i][1] += a[i] * w.y;
      acc[i][2] += a[i] * w.z;
      acc[i][3] += a[i] * w.w;
    }
  }
  float4 b1v = *(const float4*)&bl1[tx * 4];
  float4 w2v = *(const float4*)&Wl2[tx * 4];
  float bias2 = bl2[0];
  float part[TM];
#pragma unroll
  for (int i = 0; i < TM; ++i) {
    float h0 = fmaxf(acc[i][0] + b1v.x, 0.f);
    float h1 = fmaxf(acc[i][1] + b1v.y, 0.f);
    float h2 = fmaxf(acc[i][2] + b1v.z, 0.f);
    float h3 = fmaxf(acc[i][3] + b1v.w, 0.f);
    part[i] = h0 * w2v.x + h1 * w2v.y + h2 * w2v.z + h3 * w2v.w;
  }
#pragma unroll
  for (int i = 0; i < TM; ++i) {
#pragma unroll
    for (int m = 1; m < 16; m <<= 1)
      part[i] += __shfl_xor(part[i], m, 64);  // reduce across the 16 tx lanes
  }
  if (tx == 0) {
#pragma unroll
    for (int i = 0; i < TM; ++i) {
      int row = rowbase + ty * TM + i;
      if (row < nlab) out[row] = part[i] + bias2;
    }
  }
}

// ---------------- launcher ----------------

extern "C" void kernel_launch(void* const* d_in, const int* in_sizes, int n_in,
                              void* d_out, int out_size, void* d_ws, size_t ws_size,
                              hipStream_t stream) {
  const float* x   = (const float*)d_in[0];
  const int*   ei  = (const int*)d_in[1];
  const int*   eli = (const int*)d_in[2];
  const float* W1  = (const float*)d_in[3];
  const float* b1  = (const float*)d_in[4];
  const float* W2  = (const float*)d_in[5];
  const float* b2  = (const float*)d_in[6];
  const float* W3  = (const float*)d_in[7];
  const float* b3  = (const float*)d_in[8];
  const float* Wl1 = (const float*)d_in[9];
  const float* bl1 = (const float*)d_in[10];
  const float* Wl2 = (const float*)d_in[11];
  const float* bl2 = (const float*)d_in[12];
  float* out = (float*)d_out;
  const int n    = in_sizes[0] / 128;
  const int E    = in_sizes[1] / 2;
  const int nlab = in_sizes[2] / 2;
  (void)n_in; (void)out_size; (void)ws_size;

  char* ws = (char*)d_ws;
  size_t off = 0;
  auto alloc = [&](size_t bytes) -> void* {
    void* p = ws + off;
    off = (off + bytes + 255) & ~(size_t)255;
    return p;
  };
  float* bufA = (float*)alloc((size_t)n * 128 * 4);
  float* bufB = (float*)alloc((size_t)n * 128 * 4);
  int2*  csr  = (int2*)alloc((size_t)E * 8);
  int*   cnt  = (int*)alloc((size_t)n * 4);
  float* isq  = (float*)alloc((size_t)n * 4);
  int*   rs   = (int*)alloc((size_t)(n + 1) * 4);
  int*   cur  = (int*)alloc((size_t)n * 4);
  const int nb = (n + 255) / 256;  // 391 for n=100000 (must be <=512 for k_scan2)
  int*   bsum = (int*)alloc((size_t)nb * 4);

  hipMemsetAsync(cnt, 0, (size_t)n * 4, stream);
  k_hist<<<(E + 255) / 256, 256, 0, stream>>>(ei, E, cnt);
  k_scan1<<<nb, 256, 0, stream>>>(cnt, bsum, n);
  k_scan2<<<1, 512, 0, stream>>>(bsum, nb, rs, n);
  k_scan3<<<nb, 256, 0, stream>>>(cnt, bsum, rs, cur, isq, n);
  k_fill<<<(E + 255) / 256, 256, 0, stream>>>(ei, E, cur, isq, csr);

  const int tiles = (n + 63) / 64;
  const int aggb  = (n + 3) / 4;  // 4 waves (nodes) per 256-thread block
  k_gemm<128, 128><<<tiles, 256, 0, stream>>>(x, W1, bufA, n);
  k_agg<128, true><<<aggb, 256, 0, stream>>>(bufA, rs, csr, isq, b1, bufB, n);
  k_gemm<128, 64><<<tiles, 256, 0, stream>>>(bufB, W2, bufA, n);
  k_agg<64, true><<<aggb, 256, 0, stream>>>(bufA, rs, csr, isq, b2, bufB, n);
  k_gemm<64, 64><<<tiles, 256, 0, stream>>>(bufB, W3, bufA, n);
  k_agg<64, false><<<aggb, 256, 0, stream>>>(bufA, rs, csr, isq, b3, bufB, n);
  k_mlp<<<(nlab + 63) / 64, 256, 0, stream>>>(bufB, eli, nlab, Wl1, bl1, Wl2, bl2, out);
}

// Round 2
// 536.491 us; speedup vs baseline: 1.2905x; 1.2905x over previous
//
#include <hip/hip_runtime.h>

// GCN link predictor, MI355X (gfx950).
// Pipeline: memset cnt -> hist -> scan x3 -> csr fill ; wsplit x3 (f32 -> f16 hi/lo
// in MFMA B-frag layout) ; gemm1(MFMA) -> agg(relu) -> gemm2 -> agg(relu) -> gemm3
// -> agg -> fused MLP.
// GEMMs use f16-split-x3 MFMA: a = ah + al (f16), D += Ah*Bh + Ah*Bl + Al*Bh.
// Combined mantissa 22 bits -> rel err ~2^-21, accumulate in f32.

typedef _Float16 half8 __attribute__((ext_vector_type(8)));
typedef float floatx4 __attribute__((ext_vector_type(4)));

// ---------------- CSR build ----------------

__global__ void k_hist(const int* __restrict__ ei, int E, int* __restrict__ cnt) {
  int e = blockIdx.x * 256 + threadIdx.x;
  if (e < E) atomicAdd(&cnt[ei[E + e]], 1);  // dst row of edge_index
}

__global__ void k_scan1(const int* __restrict__ cnt, int* __restrict__ bsum, int n) {
  __shared__ int s[256];
  int i = blockIdx.x * 256 + threadIdx.x;
  int t = threadIdx.x;
  s[t] = (i < n) ? cnt[i] : 0;
  __syncthreads();
  for (int d = 128; d > 0; d >>= 1) {
    if (t < d) s[t] += s[t + d];
    __syncthreads();
  }
  if (t == 0) bsum[blockIdx.x] = s[0];
}

__global__ void k_scan2(int* __restrict__ bsum, int m, int* __restrict__ rs, int n) {
  __shared__ int s[512];
  int t = threadIdx.x;
  s[t] = (t < m) ? bsum[t] : 0;
  __syncthreads();
  for (int d = 1; d < 512; d <<= 1) {
    int v = (t >= d) ? s[t - d] : 0;
    __syncthreads();
    s[t] += v;
    __syncthreads();
  }
  if (t < m) bsum[t] = t ? s[t - 1] : 0;
  if (t == m - 1) rs[n] = s[t];
}

__global__ void k_scan3(const int* __restrict__ cnt, const int* __restrict__ bsum,
                        int* __restrict__ rs, int* __restrict__ cur,
                        float* __restrict__ isq, int n) {
  __shared__ int s[256];
  int i = blockIdx.x * 256 + threadIdx.x;
  int t = threadIdx.x;
  int v = (i < n) ? cnt[i] : 0;
  s[t] = v;
  __syncthreads();
  for (int d = 1; d < 256; d <<= 1) {
    int u = (t >= d) ? s[t - d] : 0;
    __syncthreads();
    s[t] += u;
    __syncthreads();
  }
  if (i < n) {
    int excl = bsum[blockIdx.x] + s[t] - v;
    rs[i] = excl;
    cur[i] = excl;
    isq[i] = rsqrtf((float)(v + 1));  // deg includes self-loop
  }
}

__global__ void k_fill(const int* __restrict__ ei, int E, int* __restrict__ cur,
                       const float* __restrict__ isq, int2* __restrict__ csr) {
  int e = blockIdx.x * 256 + threadIdx.x;
  if (e < E) {
    int s = ei[e], d = ei[E + e];
    int pos = atomicAdd(&cur[d], 1);
    csr[pos] = make_int2(s, __float_as_int(isq[s]));
  }
}

// ---------------- weight pre-split into MFMA B-fragment layout ----------------
// For mfma_f32_16x16x32_f16, B-frag: lane L holds B[k=(L>>4)*8+j][col=L&15].
// Wf layout: [ks][ct][hi/lo][lane][j] halves, each plane 512 halves.

template <int K, int C>
__global__ void k_wsplit(const float* __restrict__ W, _Float16* __restrict__ Wf) {
  int t = blockIdx.x * 256 + threadIdx.x;
  if (t >= K * C) return;
  int k = t / C, c = t % C;
  float a = W[t];
  _Float16 h = (_Float16)a;
  _Float16 l = (_Float16)(a - (float)h);
  int ks = k >> 5, ct = c >> 4;
  int lane = ((k & 31) >> 3) * 16 + (c & 15);
  int j = k & 7;
  int base = ((ks * (C / 16) + ct) * 2) * 512 + lane * 8 + j;
  Wf[base] = h;
  Wf[base + 512] = l;
}

// ---------------- MFMA GEMM: out[n,C] = A[n,K] @ W[K,C] ----------------
// Block = 4 waves, 128 rows (each wave: 2 row-groups of 16). A: global->reg->
// f16 split (read once). B: pre-split Wf staged to LDS, ds_read_b128 per frag.

template <int K, int C>
__global__ __launch_bounds__(256) void k_gemm_mfma(const float* __restrict__ A,
                                                   const _Float16* __restrict__ Wf,
                                                   float* __restrict__ out, int n) {
  constexpr int NK = K / 32, NCT = C / 16;
  constexpr int WH = NK * NCT * 2 * 512;  // halves
  __shared__ __align__(16) _Float16 Wl[WH];
  int t = threadIdx.x;
  for (int i = t; i < WH / 8; i += 256)
    ((uint4*)Wl)[i] = ((const uint4*)Wf)[i];
  __syncthreads();

  int lane = t & 63, w = t >> 6;
  int rowbase = blockIdx.x * 128 + w * 32;
  int ar0 = rowbase + (lane & 15);  // A-frag row (g=0)
  int kg = (lane >> 4) * 8;         // k offset within the 32-chunk

  floatx4 acc[2][NCT];
#pragma unroll
  for (int g = 0; g < 2; ++g)
#pragma unroll
    for (int ct = 0; ct < NCT; ++ct) acc[g][ct] = (floatx4){0.f, 0.f, 0.f, 0.f};

  for (int ks = 0; ks < NK; ++ks) {
    half8 ah[2], al[2];
#pragma unroll
    for (int g = 0; g < 2; ++g) {
      int row = ar0 + g * 16;
      if (row > n - 1) row = n - 1;  // clamp: stores are guarded
      const float* ap = A + (size_t)row * K + ks * 32 + kg;
      float4 u0 = ((const float4*)ap)[0];
      float4 u1 = ((const float4*)ap)[1];
      float av0 = u0.x, av1 = u0.y, av2 = u0.z, av3 = u0.w;
      float av4 = u1.x, av5 = u1.y, av6 = u1.z, av7 = u1.w;
      _Float16 h;
      h = (_Float16)av0; ah[g][0] = h; al[g][0] = (_Float16)(av0 - (float)h);
      h = (_Float16)av1; ah[g][1] = h; al[g][1] = (_Float16)(av1 - (float)h);
      h = (_Float16)av2; ah[g][2] = h; al[g][2] = (_Float16)(av2 - (float)h);
      h = (_Float16)av3; ah[g][3] = h; al[g][3] = (_Float16)(av3 - (float)h);
      h = (_Float16)av4; ah[g][4] = h; al[g][4] = (_Float16)(av4 - (float)h);
      h = (_Float16)av5; ah[g][5] = h; al[g][5] = (_Float16)(av5 - (float)h);
      h = (_Float16)av6; ah[g][6] = h; al[g][6] = (_Float16)(av6 - (float)h);
      h = (_Float16)av7; ah[g][7] = h; al[g][7] = (_Float16)(av7 - (float)h);
    }
#pragma unroll
    for (int ct = 0; ct < NCT; ++ct) {
      const _Float16* bp = &Wl[((ks * NCT + ct) * 2) * 512 + lane * 8];
      half8 bh = *(const half8*)bp;
      half8 bl = *(const half8*)(bp + 512);
#pragma unroll
      for (int g = 0; g < 2; ++g) {
        acc[g][ct] = __builtin_amdgcn_mfma_f32_16x16x32_f16(ah[g], bh, acc[g][ct], 0, 0, 0);
        acc[g][ct] = __builtin_amdgcn_mfma_f32_16x16x32_f16(ah[g], bl, acc[g][ct], 0, 0, 0);
        acc[g][ct] = __builtin_amdgcn_mfma_f32_16x16x32_f16(al[g], bh, acc[g][ct], 0, 0, 0);
      }
    }
  }
  // D layout: col = lane&15, row = (lane>>4)*4 + r  (per 16x16 tile)
  int drbase = rowbase + (lane >> 4) * 4;
  int col = lane & 15;
#pragma unroll
  for (int g = 0; g < 2; ++g)
#pragma unroll
    for (int ct = 0; ct < NCT; ++ct)
#pragma unroll
      for (int r = 0; r < 4; ++r) {
        int row = drbase + g * 16 + r;
        if (row < n) out[(size_t)row * C + ct * 16 + col] = acc[g][ct][r];
      }
}

// ---------------- CSR pull aggregation (unroll 4 for MLP) ----------------
// One wave per destination node; lane = channel (x2 for C=128).
// out[i] = isq[i]*(sum_e isq[src]*xw[src] + isq[i]*xw[i]) + b  (+relu)

template <int C, bool RELU>
__global__ __launch_bounds__(256) void k_agg(const float* __restrict__ xw,
                                             const int* __restrict__ rs,
                                             const int2* __restrict__ csr,
                                             const float* __restrict__ isq,
                                             const float* __restrict__ bias,
                                             float* __restrict__ out, int n) {
  int gw = (int)((blockIdx.x * blockDim.x + threadIdx.x) >> 6);
  int lane = threadIdx.x & 63;
  if (gw >= n) return;
  int e0 = rs[gw], e1 = rs[gw + 1];
  if (C == 128) {
    float acc0 = 0.f, acc1 = 0.f;
    int e = e0;
    for (; e + 4 <= e1; e += 4) {
      int2 a = csr[e], b = csr[e + 1], c = csr[e + 2], d = csr[e + 3];
      float2 va = *(const float2*)&xw[(size_t)a.x * 128 + 2 * lane];
      float2 vb = *(const float2*)&xw[(size_t)b.x * 128 + 2 * lane];
      float2 vc = *(const float2*)&xw[(size_t)c.x * 128 + 2 * lane];
      float2 vd = *(const float2*)&xw[(size_t)d.x * 128 + 2 * lane];
      float wa = __int_as_float(a.y), wb = __int_as_float(b.y);
      float wc = __int_as_float(c.y), wd = __int_as_float(d.y);
      acc0 += wa * va.x + wb * vb.x + wc * vc.x + wd * vd.x;
      acc1 += wa * va.y + wb * vb.y + wc * vc.y + wd * vd.y;
    }
    for (; e < e1; ++e) {
      int2 a = csr[e];
      float2 va = *(const float2*)&xw[(size_t)a.x * 128 + 2 * lane];
      float wa = __int_as_float(a.y);
      acc0 += wa * va.x;
      acc1 += wa * va.y;
    }
    float qi = isq[gw];
    float2 self = *(const float2*)&xw[(size_t)gw * 128 + 2 * lane];
    float r0 = qi * (acc0 + qi * self.x) + bias[2 * lane];
    float r1 = qi * (acc1 + qi * self.y) + bias[2 * lane + 1];
    if (RELU) { r0 = fmaxf(r0, 0.f); r1 = fmaxf(r1, 0.f); }
    *(float2*)&out[(size_t)gw * 128 + 2 * lane] = make_float2(r0, r1);
  } else {
    float acc = 0.f;
    int e = e0;
    for (; e + 4 <= e1; e += 4) {
      int2 a = csr[e], b = csr[e + 1], c = csr[e + 2], d = csr[e + 3];
      float va = xw[(size_t)a.x * C + lane];
      float vb = xw[(size_t)b.x * C + lane];
      float vc = xw[(size_t)c.x * C + lane];
      float vd = xw[(size_t)d.x * C + lane];
      acc += __int_as_float(a.y) * va + __int_as_float(b.y) * vb +
             __int_as_float(c.y) * vc + __int_as_float(d.y) * vd;
    }
    for (; e < e1; ++e) {
      int2 a = csr[e];
      acc += __int_as_float(a.y) * xw[(size_t)a.x * C + lane];
    }
    float qi = isq[gw];
    float self = xw[(size_t)gw * C + lane];
    float r = qi * (acc + qi * self) + bias[lane];
    if (RELU) r = fmaxf(r, 0.f);
    out[(size_t)gw * C + lane] = r;
  }
}

// ---------------- fused link MLP ----------------

__global__ __launch_bounds__(256) void k_mlp(const float* __restrict__ z,
                                             const int* __restrict__ eli, int nlab,
                                             const float* __restrict__ Wl1,
                                             const float* __restrict__ bl1,
                                             const float* __restrict__ Wl2,
                                             const float* __restrict__ bl2,
                                             float* __restrict__ out) {
  constexpr int K = 128, TM = 4, LDA = K + 4;
  __shared__ float Wl[K * 64];
  __shared__ float Al[64 * LDA];
  int t = threadIdx.x;
  for (int i = t; i < K * 64 / 4; i += 256)
    ((float4*)Wl)[i] = ((const float4*)Wl1)[i];
  int rowbase = blockIdx.x * 64;
  {
    int r = t >> 2, p = t & 3;  // 4 threads/row; p<2 -> z[s], p>=2 -> z[d]
    int row = rowbase + r;
    int idx = 0;
    if (row < nlab) idx = (p < 2) ? eli[row] : eli[nlab + row];
    const float4* src = (const float4*)(z + (size_t)idx * 64);
    int srcq = (p & 1) * 8;
    int dst = r * LDA + (p >= 2 ? 64 : 0) + (p & 1) * 32;
#pragma unroll
    for (int q = 0; q < 8; ++q)
      *(float4*)&Al[dst + 4 * q] = src[srcq + q];
  }
  __syncthreads();
  int tx = t & 15, ty = t >> 4;
  float acc[TM][4] = {};
  for (int k = 0; k < K; ++k) {
    float a[TM];
#pragma unroll
    for (int i = 0; i < TM; ++i) a[i] = Al[(ty * TM + i) * LDA + k];
    float4 w = *(const float4*)&Wl[k * 64 + tx * 4];
#pragma unroll
    for (int i = 0; i < TM; ++i) {
      acc[i][0] += a[i] * w.x;
      acc[i][1] += a[i] * w.y;
      acc[i][2] += a[i] * w.z;
      acc[i][3] += a[i] * w.w;
    }
  }
  float4 b1v = *(const float4*)&bl1[tx * 4];
  float4 w2v = *(const float4*)&Wl2[tx * 4];
  float bias2 = bl2[0];
  float part[TM];
#pragma unroll
  for (int i = 0; i < TM; ++i) {
    float h0 = fmaxf(acc[i][0] + b1v.x, 0.f);
    float h1 = fmaxf(acc[i][1] + b1v.y, 0.f);
    float h2 = fmaxf(acc[i][2] + b1v.z, 0.f);
    float h3 = fmaxf(acc[i][3] + b1v.w, 0.f);
    part[i] = h0 * w2v.x + h1 * w2v.y + h2 * w2v.z + h3 * w2v.w;
  }
#pragma unroll
  for (int i = 0; i < TM; ++i) {
#pragma unroll
    for (int m = 1; m < 16; m <<= 1)
      part[i] += __shfl_xor(part[i], m, 64);
  }
  if (tx == 0) {
#pragma unroll
    for (int i = 0; i < TM; ++i) {
      int row = rowbase + ty * TM + i;
      if (row < nlab) out[row] = part[i] + bias2;
    }
  }
}

// ---------------- launcher ----------------

extern "C" void kernel_launch(void* const* d_in, const int* in_sizes, int n_in,
                              void* d_out, int out_size, void* d_ws, size_t ws_size,
                              hipStream_t stream) {
  const float* x   = (const float*)d_in[0];
  const int*   ei  = (const int*)d_in[1];
  const int*   eli = (const int*)d_in[2];
  const float* W1  = (const float*)d_in[3];
  const float* b1  = (const float*)d_in[4];
  const float* W2  = (const float*)d_in[5];
  const float* b2  = (const float*)d_in[6];
  const float* W3  = (const float*)d_in[7];
  const float* b3  = (const float*)d_in[8];
  const float* Wl1 = (const float*)d_in[9];
  const float* bl1 = (const float*)d_in[10];
  const float* Wl2 = (const float*)d_in[11];
  const float* bl2 = (const float*)d_in[12];
  float* out = (float*)d_out;
  const int n    = in_sizes[0] / 128;
  const int E    = in_sizes[1] / 2;
  const int nlab = in_sizes[2] / 2;
  (void)n_in; (void)out_size; (void)ws_size;

  char* ws = (char*)d_ws;
  size_t off = 0;
  auto alloc = [&](size_t bytes) -> void* {
    void* p = ws + off;
    off = (off + bytes + 255) & ~(size_t)255;
    return p;
  };
  float*     bufA = (float*)alloc((size_t)n * 128 * 4);
  float*     bufB = (float*)alloc((size_t)n * 128 * 4);
  int2*      csr  = (int2*)alloc((size_t)E * 8);
  int*       cnt  = (int*)alloc((size_t)n * 4);
  float*     isq  = (float*)alloc((size_t)n * 4);
  int*       rs   = (int*)alloc((size_t)(n + 1) * 4);
  int*       cur  = (int*)alloc((size_t)n * 4);
  const int  nb   = (n + 255) / 256;  // 391 for n=100000 (<=512 for k_scan2)
  int*       bsum = (int*)alloc((size_t)nb * 4);
  _Float16*  Wf1  = (_Float16*)alloc(128 * 128 * 2 * 2);
  _Float16*  Wf2  = (_Float16*)alloc(128 * 64 * 2 * 2);
  _Float16*  Wf3  = (_Float16*)alloc(64 * 64 * 2 * 2);

  hipMemsetAsync(cnt, 0, (size_t)n * 4, stream);
  k_hist<<<(E + 255) / 256, 256, 0, stream>>>(ei, E, cnt);
  k_scan1<<<nb, 256, 0, stream>>>(cnt, bsum, n);
  k_scan2<<<1, 512, 0, stream>>>(bsum, nb, rs, n);
  k_scan3<<<nb, 256, 0, stream>>>(cnt, bsum, rs, cur, isq, n);
  k_fill<<<(E + 255) / 256, 256, 0, stream>>>(ei, E, cur, isq, csr);

  k_wsplit<128, 128><<<(128 * 128 + 255) / 256, 256, 0, stream>>>(W1, Wf1);
  k_wsplit<128, 64><<<(128 * 64 + 255) / 256, 256, 0, stream>>>(W2, Wf2);
  k_wsplit<64, 64><<<(64 * 64 + 255) / 256, 256, 0, stream>>>(W3, Wf3);

  const int gtiles = (n + 127) / 128;
  const int aggb   = (n + 3) / 4;  // 4 waves (nodes) per 256-thread block
  k_gemm_mfma<128, 128><<<gtiles, 256, 0, stream>>>(x, Wf1, bufA, n);
  k_agg<128, true><<<aggb, 256, 0, stream>>>(bufA, rs, csr, isq, b1, bufB, n);
  k_gemm_mfma<128, 64><<<gtiles, 256, 0, stream>>>(bufB, Wf2, bufA, n);
  k_agg<64, true><<<aggb, 256, 0, stream>>>(bufA, rs, csr, isq, b2, bufB, n);
  k_gemm_mfma<64, 64><<<gtiles, 256, 0, stream>>>(bufB, Wf3, bufA, n);
  k_agg<64, false><<<aggb, 256, 0, stream>>>(bufA, rs, csr, isq, b3, bufB, n);
  k_mlp<<<(nlab + 63) / 64, 256, 0, stream>>>(bufB, eli, nlab, Wl1, bl1, Wl2, bl2, out);
}

// Round 3
// 531.848 us; speedup vs baseline: 1.3018x; 1.0087x over previous
//
#include <hip/hip_runtime.h>

// GCN link predictor, MI355X (gfx950).
// Pipeline: memset cnt -> hist -> scan x3 -> csr fill ; wsplit x3 (f32 -> f16 hi/lo
// in MFMA B-frag layout) ; gemm1(MFMA) -> agg(relu) -> gemm2 -> agg(relu) -> gemm3
// -> agg -> fused MLP.
// GEMMs: f16-split-x3 MFMA (a = ah+al, D += Ah*Bh + Ah*Bl + Al*Bh), f32 accum.
// Aggs: half-wave per edge (lanes 0-31 even edges, 32-63 odd), float4/float2 per
// lane, 4-deep unroll = 8 edge-rows in flight per wave; shfl_xor(32) combine.

typedef _Float16 half8 __attribute__((ext_vector_type(8)));
typedef float floatx4 __attribute__((ext_vector_type(4)));

// ---------------- CSR build ----------------

__global__ void k_hist(const int* __restrict__ ei, int E, int* __restrict__ cnt) {
  int e = blockIdx.x * 256 + threadIdx.x;
  if (e < E) atomicAdd(&cnt[ei[E + e]], 1);  // dst row of edge_index
}

__global__ void k_scan1(const int* __restrict__ cnt, int* __restrict__ bsum, int n) {
  __shared__ int s[256];
  int i = blockIdx.x * 256 + threadIdx.x;
  int t = threadIdx.x;
  s[t] = (i < n) ? cnt[i] : 0;
  __syncthreads();
  for (int d = 128; d > 0; d >>= 1) {
    if (t < d) s[t] += s[t + d];
    __syncthreads();
  }
  if (t == 0) bsum[blockIdx.x] = s[0];
}

__global__ void k_scan2(int* __restrict__ bsum, int m, int* __restrict__ rs, int n) {
  __shared__ int s[512];
  int t = threadIdx.x;
  s[t] = (t < m) ? bsum[t] : 0;
  __syncthreads();
  for (int d = 1; d < 512; d <<= 1) {
    int v = (t >= d) ? s[t - d] : 0;
    __syncthreads();
    s[t] += v;
    __syncthreads();
  }
  if (t < m) bsum[t] = t ? s[t - 1] : 0;
  if (t == m - 1) rs[n] = s[t];
}

__global__ void k_scan3(const int* __restrict__ cnt, const int* __restrict__ bsum,
                        int* __restrict__ rs, int* __restrict__ cur,
                        float* __restrict__ isq, int n) {
  __shared__ int s[256];
  int i = blockIdx.x * 256 + threadIdx.x;
  int t = threadIdx.x;
  int v = (i < n) ? cnt[i] : 0;
  s[t] = v;
  __syncthreads();
  for (int d = 1; d < 256; d <<= 1) {
    int u = (t >= d) ? s[t - d] : 0;
    __syncthreads();
    s[t] += u;
    __syncthreads();
  }
  if (i < n) {
    int excl = bsum[blockIdx.x] + s[t] - v;
    rs[i] = excl;
    cur[i] = excl;
    isq[i] = rsqrtf((float)(v + 1));  // deg includes self-loop
  }
}

__global__ void k_fill(const int* __restrict__ ei, int E, int* __restrict__ cur,
                       const float* __restrict__ isq, int2* __restrict__ csr) {
  int e = blockIdx.x * 256 + threadIdx.x;
  if (e < E) {
    int s = ei[e], d = ei[E + e];
    int pos = atomicAdd(&cur[d], 1);
    csr[pos] = make_int2(s, __float_as_int(isq[s]));
  }
}

// ---------------- weight pre-split into MFMA B-fragment layout ----------------

template <int K, int C>
__global__ void k_wsplit(const float* __restrict__ W, _Float16* __restrict__ Wf) {
  int t = blockIdx.x * 256 + threadIdx.x;
  if (t >= K * C) return;
  int k = t / C, c = t % C;
  float a = W[t];
  _Float16 h = (_Float16)a;
  _Float16 l = (_Float16)(a - (float)h);
  int ks = k >> 5, ct = c >> 4;
  int lane = ((k & 31) >> 3) * 16 + (c & 15);
  int j = k & 7;
  int base = ((ks * (C / 16) + ct) * 2) * 512 + lane * 8 + j;
  Wf[base] = h;
  Wf[base + 512] = l;
}

// ---------------- MFMA GEMM: out[n,C] = A[n,K] @ W[K,C] ----------------

template <int K, int C>
__global__ __launch_bounds__(256) void k_gemm_mfma(const float* __restrict__ A,
                                                   const _Float16* __restrict__ Wf,
                                                   float* __restrict__ out, int n) {
  constexpr int NK = K / 32, NCT = C / 16;
  constexpr int WH = NK * NCT * 2 * 512;  // halves
  __shared__ __align__(16) _Float16 Wl[WH];
  int t = threadIdx.x;
  for (int i = t; i < WH / 8; i += 256)
    ((uint4*)Wl)[i] = ((const uint4*)Wf)[i];
  __syncthreads();

  int lane = t & 63, w = t >> 6;
  int rowbase = blockIdx.x * 128 + w * 32;
  int ar0 = rowbase + (lane & 15);
  int kg = (lane >> 4) * 8;

  floatx4 acc[2][NCT];
#pragma unroll
  for (int g = 0; g < 2; ++g)
#pragma unroll
    for (int ct = 0; ct < NCT; ++ct) acc[g][ct] = (floatx4){0.f, 0.f, 0.f, 0.f};

  for (int ks = 0; ks < NK; ++ks) {
    half8 ah[2], al[2];
#pragma unroll
    for (int g = 0; g < 2; ++g) {
      int row = ar0 + g * 16;
      if (row > n - 1) row = n - 1;  // clamp: stores are guarded
      const float* ap = A + (size_t)row * K + ks * 32 + kg;
      float4 u0 = ((const float4*)ap)[0];
      float4 u1 = ((const float4*)ap)[1];
      float av[8] = {u0.x, u0.y, u0.z, u0.w, u1.x, u1.y, u1.z, u1.w};
#pragma unroll
      for (int q = 0; q < 8; ++q) {
        _Float16 h = (_Float16)av[q];
        ah[g][q] = h;
        al[g][q] = (_Float16)(av[q] - (float)h);
      }
    }
#pragma unroll
    for (int ct = 0; ct < NCT; ++ct) {
      const _Float16* bp = &Wl[((ks * NCT + ct) * 2) * 512 + lane * 8];
      half8 bh = *(const half8*)bp;
      half8 bl = *(const half8*)(bp + 512);
#pragma unroll
      for (int g = 0; g < 2; ++g) {
        acc[g][ct] = __builtin_amdgcn_mfma_f32_16x16x32_f16(ah[g], bh, acc[g][ct], 0, 0, 0);
        acc[g][ct] = __builtin_amdgcn_mfma_f32_16x16x32_f16(ah[g], bl, acc[g][ct], 0, 0, 0);
        acc[g][ct] = __builtin_amdgcn_mfma_f32_16x16x32_f16(al[g], bh, acc[g][ct], 0, 0, 0);
      }
    }
  }
  int drbase = rowbase + (lane >> 4) * 4;
  int col = lane & 15;
#pragma unroll
  for (int g = 0; g < 2; ++g)
#pragma unroll
    for (int ct = 0; ct < NCT; ++ct)
#pragma unroll
      for (int r = 0; r < 4; ++r) {
        int row = drbase + g * 16 + r;
        if (row < n) out[(size_t)row * C + ct * 16 + col] = acc[g][ct][r];
      }
}

// ---------------- CSR pull aggregation, half-wave per edge ----------------
// C=128: lane reads float4 of its edge's row (32 lanes x 16B = 512B row).
// C=64:  lane reads float2 (32 lanes x 8B = 256B row).
// Lanes 0-31 take edges e0,e0+2,...; lanes 32-63 take e0+1,e0+3,...
// 4-deep unroll -> 8 edge rows in flight per wave. shfl_xor(32) combines.

template <bool RELU>
__global__ __launch_bounds__(256) void k_agg128(const float* __restrict__ xw,
                                                const int* __restrict__ rs,
                                                const int2* __restrict__ csr,
                                                const float* __restrict__ isq,
                                                const float* __restrict__ bias,
                                                float* __restrict__ out, int n) {
  int gw = (int)((blockIdx.x * blockDim.x + threadIdx.x) >> 6);
  int lane = threadIdx.x & 63;
  if (gw >= n) return;
  int e0 = rs[gw], e1 = rs[gw + 1];
  int half = lane >> 5, sub = lane & 31;
  float4 acc = make_float4(0.f, 0.f, 0.f, 0.f);
  int e = e0 + half;
  for (; e + 6 < e1; e += 8) {
    int2 a = csr[e], b = csr[e + 2], c = csr[e + 4], d = csr[e + 6];
    float4 va = *(const float4*)&xw[(size_t)a.x * 128 + 4 * sub];
    float4 vb = *(const float4*)&xw[(size_t)b.x * 128 + 4 * sub];
    float4 vc = *(const float4*)&xw[(size_t)c.x * 128 + 4 * sub];
    float4 vd = *(const float4*)&xw[(size_t)d.x * 128 + 4 * sub];
    float wa = __int_as_float(a.y), wb = __int_as_float(b.y);
    float wc = __int_as_float(c.y), wd = __int_as_float(d.y);
    acc.x += wa * va.x + wb * vb.x + wc * vc.x + wd * vd.x;
    acc.y += wa * va.y + wb * vb.y + wc * vc.y + wd * vd.y;
    acc.z += wa * va.z + wb * vb.z + wc * vc.z + wd * vd.z;
    acc.w += wa * va.w + wb * vb.w + wc * vc.w + wd * vd.w;
  }
  for (; e < e1; e += 2) {
    int2 a = csr[e];
    float4 va = *(const float4*)&xw[(size_t)a.x * 128 + 4 * sub];
    float wa = __int_as_float(a.y);
    acc.x += wa * va.x;
    acc.y += wa * va.y;
    acc.z += wa * va.z;
    acc.w += wa * va.w;
  }
  acc.x += __shfl_xor(acc.x, 32, 64);
  acc.y += __shfl_xor(acc.y, 32, 64);
  acc.z += __shfl_xor(acc.z, 32, 64);
  acc.w += __shfl_xor(acc.w, 32, 64);
  if (half == 0) {
    float qi = isq[gw];
    float4 self = *(const float4*)&xw[(size_t)gw * 128 + 4 * sub];
    float4 bv = *(const float4*)&bias[4 * sub];
    float4 r;
    r.x = qi * (acc.x + qi * self.x) + bv.x;
    r.y = qi * (acc.y + qi * self.y) + bv.y;
    r.z = qi * (acc.z + qi * self.z) + bv.z;
    r.w = qi * (acc.w + qi * self.w) + bv.w;
    if (RELU) {
      r.x = fmaxf(r.x, 0.f); r.y = fmaxf(r.y, 0.f);
      r.z = fmaxf(r.z, 0.f); r.w = fmaxf(r.w, 0.f);
    }
    *(float4*)&out[(size_t)gw * 128 + 4 * sub] = r;
  }
}

template <bool RELU>
__global__ __launch_bounds__(256) void k_agg64(const float* __restrict__ xw,
                                               const int* __restrict__ rs,
                                               const int2* __restrict__ csr,
                                               const float* __restrict__ isq,
                                               const float* __restrict__ bias,
                                               float* __restrict__ out, int n) {
  int gw = (int)((blockIdx.x * blockDim.x + threadIdx.x) >> 6);
  int lane = threadIdx.x & 63;
  if (gw >= n) return;
  int e0 = rs[gw], e1 = rs[gw + 1];
  int half = lane >> 5, sub = lane & 31;
  float acc0 = 0.f, acc1 = 0.f;
  int e = e0 + half;
  for (; e + 6 < e1; e += 8) {
    int2 a = csr[e], b = csr[e + 2], c = csr[e + 4], d = csr[e + 6];
    float2 va = *(const float2*)&xw[(size_t)a.x * 64 + 2 * sub];
    float2 vb = *(const float2*)&xw[(size_t)b.x * 64 + 2 * sub];
    float2 vc = *(const float2*)&xw[(size_t)c.x * 64 + 2 * sub];
    float2 vd = *(const float2*)&xw[(size_t)d.x * 64 + 2 * sub];
    float wa = __int_as_float(a.y), wb = __int_as_float(b.y);
    float wc = __int_as_float(c.y), wd = __int_as_float(d.y);
    acc0 += wa * va.x + wb * vb.x + wc * vc.x + wd * vd.x;
    acc1 += wa * va.y + wb * vb.y + wc * vc.y + wd * vd.y;
  }
  for (; e < e1; e += 2) {
    int2 a = csr[e];
    float2 va = *(const float2*)&xw[(size_t)a.x * 64 + 2 * sub];
    float wa = __int_as_float(a.y);
    acc0 += wa * va.x;
    acc1 += wa * va.y;
  }
  acc0 += __shfl_xor(acc0, 32, 64);
  acc1 += __shfl_xor(acc1, 32, 64);
  if (half == 0) {
    float qi = isq[gw];
    float2 self = *(const float2*)&xw[(size_t)gw * 64 + 2 * sub];
    float r0 = qi * (acc0 + qi * self.x) + bias[2 * sub];
    float r1 = qi * (acc1 + qi * self.y) + bias[2 * sub + 1];
    if (RELU) { r0 = fmaxf(r0, 0.f); r1 = fmaxf(r1, 0.f); }
    *(float2*)&out[(size_t)gw * 64 + 2 * sub] = make_float2(r0, r1);
  }
}

// ---------------- fused link MLP ----------------

__global__ __launch_bounds__(256) void k_mlp(const float* __restrict__ z,
                                             const int* __restrict__ eli, int nlab,
                                             const float* __restrict__ Wl1,
                                             const float* __restrict__ bl1,
                                             const float* __restrict__ Wl2,
                                             const float* __restrict__ bl2,
                                             float* __restrict__ out) {
  constexpr int K = 128, TM = 4, LDA = K + 4;
  __shared__ float Wl[K * 64];
  __shared__ float Al[64 * LDA];
  int t = threadIdx.x;
  for (int i = t; i < K * 64 / 4; i += 256)
    ((float4*)Wl)[i] = ((const float4*)Wl1)[i];
  int rowbase = blockIdx.x * 64;
  {
    int r = t >> 2, p = t & 3;  // 4 threads/row; p<2 -> z[s], p>=2 -> z[d]
    int row = rowbase + r;
    int idx = 0;
    if (row < nlab) idx = (p < 2) ? eli[row] : eli[nlab + row];
    const float4* src = (const float4*)(z + (size_t)idx * 64);
    int srcq = (p & 1) * 8;
    int dst = r * LDA + (p >= 2 ? 64 : 0) + (p & 1) * 32;
#pragma unroll
    for (int q = 0; q < 8; ++q)
      *(float4*)&Al[dst + 4 * q] = src[srcq + q];
  }
  __syncthreads();
  int tx = t & 15, ty = t >> 4;
  float acc[TM][4] = {};
  for (int k = 0; k < K; ++k) {
    float a[TM];
#pragma unroll
    for (int i = 0; i < TM; ++i) a[i] = Al[(ty * TM + i) * LDA + k];
    float4 w = *(const float4*)&Wl[k * 64 + tx * 4];
#pragma unroll
    for (int i = 0; i < TM; ++i) {
      acc[i][0] += a[i] * w.x;
      acc[i][1] += a[i] * w.y;
      acc[i][2] += a[i] * w.z;
      acc[i][3] += a[i] * w.w;
    }
  }
  float4 b1v = *(const float4*)&bl1[tx * 4];
  float4 w2v = *(const float4*)&Wl2[tx * 4];
  float bias2 = bl2[0];
  float part[TM];
#pragma unroll
  for (int i = 0; i < TM; ++i) {
    float h0 = fmaxf(acc[i][0] + b1v.x, 0.f);
    float h1 = fmaxf(acc[i][1] + b1v.y, 0.f);
    float h2 = fmaxf(acc[i][2] + b1v.z, 0.f);
    float h3 = fmaxf(acc[i][3] + b1v.w, 0.f);
    part[i] = h0 * w2v.x + h1 * w2v.y + h2 * w2v.z + h3 * w2v.w;
  }
#pragma unroll
  for (int i = 0; i < TM; ++i) {
#pragma unroll
    for (int m = 1; m < 16; m <<= 1)
      part[i] += __shfl_xor(part[i], m, 64);
  }
  if (tx == 0) {
#pragma unroll
    for (int i = 0; i < TM; ++i) {
      int row = rowbase + ty * TM + i;
      if (row < nlab) out[row] = part[i] + bias2;
    }
  }
}

// ---------------- launcher ----------------

extern "C" void kernel_launch(void* const* d_in, const int* in_sizes, int n_in,
                              void* d_out, int out_size, void* d_ws, size_t ws_size,
                              hipStream_t stream) {
  const float* x   = (const float*)d_in[0];
  const int*   ei  = (const int*)d_in[1];
  const int*   eli = (const int*)d_in[2];
  const float* W1  = (const float*)d_in[3];
  const float* b1  = (const float*)d_in[4];
  const float* W2  = (const float*)d_in[5];
  const float* b2  = (const float*)d_in[6];
  const float* W3  = (const float*)d_in[7];
  const float* b3  = (const float*)d_in[8];
  const float* Wl1 = (const float*)d_in[9];
  const float* bl1 = (const float*)d_in[10];
  const float* Wl2 = (const float*)d_in[11];
  const float* bl2 = (const float*)d_in[12];
  float* out = (float*)d_out;
  const int n    = in_sizes[0] / 128;
  const int E    = in_sizes[1] / 2;
  const int nlab = in_sizes[2] / 2;
  (void)n_in; (void)out_size; (void)ws_size;

  char* ws = (char*)d_ws;
  size_t off = 0;
  auto alloc = [&](size_t bytes) -> void* {
    void* p = ws + off;
    off = (off + bytes + 255) & ~(size_t)255;
    return p;
  };
  float*     bufA = (float*)alloc((size_t)n * 128 * 4);
  float*     bufB = (float*)alloc((size_t)n * 128 * 4);
  int2*      csr  = (int2*)alloc((size_t)E * 8);
  int*       cnt  = (int*)alloc((size_t)n * 4);
  float*     isq  = (float*)alloc((size_t)n * 4);
  int*       rs   = (int*)alloc((size_t)(n + 1) * 4);
  int*       cur  = (int*)alloc((size_t)n * 4);
  const int  nb   = (n + 255) / 256;  // 391 for n=100000 (<=512 for k_scan2)
  int*       bsum = (int*)alloc((size_t)nb * 4);
  _Float16*  Wf1  = (_Float16*)alloc(128 * 128 * 2 * 2);
  _Float16*  Wf2  = (_Float16*)alloc(128 * 64 * 2 * 2);
  _Float16*  Wf3  = (_Float16*)alloc(64 * 64 * 2 * 2);

  hipMemsetAsync(cnt, 0, (size_t)n * 4, stream);
  k_hist<<<(E + 255) / 256, 256, 0, stream>>>(ei, E, cnt);
  k_scan1<<<nb, 256, 0, stream>>>(cnt, bsum, n);
  k_scan2<<<1, 512, 0, stream>>>(bsum, nb, rs, n);
  k_scan3<<<nb, 256, 0, stream>>>(cnt, bsum, rs, cur, isq, n);
  k_fill<<<(E + 255) / 256, 256, 0, stream>>>(ei, E, cur, isq, csr);

  k_wsplit<128, 128><<<(128 * 128 + 255) / 256, 256, 0, stream>>>(W1, Wf1);
  k_wsplit<128, 64><<<(128 * 64 + 255) / 256, 256, 0, stream>>>(W2, Wf2);
  k_wsplit<64, 64><<<(64 * 64 + 255) / 256, 256, 0, stream>>>(W3, Wf3);

  const int gtiles = (n + 127) / 128;
  const int aggb   = (n + 3) / 4;  // 4 waves (nodes) per 256-thread block
  k_gemm_mfma<128, 128><<<gtiles, 256, 0, stream>>>(x, Wf1, bufA, n);
  k_agg128<true><<<aggb, 256, 0, stream>>>(bufA, rs, csr, isq, b1, bufB, n);
  k_gemm_mfma<128, 64><<<gtiles, 256, 0, stream>>>(bufB, Wf2, bufA, n);
  k_agg64<true><<<aggb, 256, 0, stream>>>(bufA, rs, csr, isq, b2, bufB, n);
  k_gemm_mfma<64, 64><<<gtiles, 256, 0, stream>>>(bufB, Wf3, bufA, n);
  k_agg64<false><<<aggb, 256, 0, stream>>>(bufA, rs, csr, isq, b3, bufB, n);
  k_mlp<<<(nlab + 63) / 64, 256, 0, stream>>>(bufB, eli, nlab, Wl1, bl1, Wl2, bl2, out);
}

// Round 4
// 528.695 us; speedup vs baseline: 1.3095x; 1.0060x over previous
//
#include <hip/hip_runtime.h>

// GCN link predictor, MI355X (gfx950).
// Round 4: csr payload = 4B src only (isq folded into GEMM epilogue prescale:
// xs = isq .* (h@W), conv[i] = isq[i]*(sum xs[src] + xs[i]) + b);
// k_fill fused into gemm1 (independent work, role-split grid);
// wsplit x3 fused into k_hist; agg64 quarter-wave float4.

typedef _Float16 half8 __attribute__((ext_vector_type(8)));
typedef float floatx4 __attribute__((ext_vector_type(4)));

// ---------------- fused hist + weight split ----------------
// blocks [0,HB): histogram of dst. blocks [HB, HB+112): f32->f16 hi/lo split of
// W1/W2/W3 into MFMA B-frag layout (lane L holds B[k=(L>>4)*8+j][col=L&15]).

__global__ __launch_bounds__(256) void k_hist_wsplit(
    const int* __restrict__ ei, int E, int* __restrict__ cnt,
    const float* __restrict__ W1, _Float16* __restrict__ Wf1,
    const float* __restrict__ W2, _Float16* __restrict__ Wf2,
    const float* __restrict__ W3, _Float16* __restrict__ Wf3, int HB) {
  int b = blockIdx.x;
  if (b < HB) {
    int e = b * 256 + threadIdx.x;
    if (e < E) atomicAdd(&cnt[__builtin_nontemporal_load(ei + E + e)], 1);
    return;
  }
  b -= HB;
  const float* W;
  _Float16* Wf;
  int KC, lc;
  if (b < 64)      { W = W1; Wf = Wf1; KC = 16384; lc = 7; }
  else if (b < 96) { b -= 64; W = W2; Wf = Wf2; KC = 8192; lc = 6; }
  else             { b -= 96; W = W3; Wf = Wf3; KC = 4096; lc = 6; }
  int t = b * 256 + threadIdx.x;
  if (t >= KC) return;
  int C = 1 << lc;
  int c = t & (C - 1), k = t >> lc;
  float a = W[t];
  _Float16 h = (_Float16)a;
  _Float16 l = (_Float16)(a - (float)h);
  int ks = k >> 5, ct = c >> 4;
  int lane = ((k & 31) >> 3) * 16 + (c & 15);
  int j = k & 7;
  int base = ((ks * (C >> 4) + ct) * 2) * 512 + lane * 8 + j;
  Wf[base] = h;
  Wf[base + 512] = l;
}

// ---------------- scans ----------------

__global__ void k_scan1(const int* __restrict__ cnt, int* __restrict__ bsum, int n) {
  __shared__ int s[256];
  int i = blockIdx.x * 256 + threadIdx.x;
  int t = threadIdx.x;
  s[t] = (i < n) ? cnt[i] : 0;
  __syncthreads();
  for (int d = 128; d > 0; d >>= 1) {
    if (t < d) s[t] += s[t + d];
    __syncthreads();
  }
  if (t == 0) bsum[blockIdx.x] = s[0];
}

__global__ void k_scan2(int* __restrict__ bsum, int m, int* __restrict__ rs, int n) {
  __shared__ int s[512];
  int t = threadIdx.x;
  s[t] = (t < m) ? bsum[t] : 0;
  __syncthreads();
  for (int d = 1; d < 512; d <<= 1) {
    int v = (t >= d) ? s[t - d] : 0;
    __syncthreads();
    s[t] += v;
    __syncthreads();
  }
  if (t < m) bsum[t] = t ? s[t - 1] : 0;
  if (t == m - 1) rs[n] = s[t];
}

__global__ void k_scan3(const int* __restrict__ cnt, const int* __restrict__ bsum,
                        int* __restrict__ rs, int* __restrict__ cur,
                        float* __restrict__ isq, int n) {
  __shared__ int s[256];
  int i = blockIdx.x * 256 + threadIdx.x;
  int t = threadIdx.x;
  int v = (i < n) ? cnt[i] : 0;
  s[t] = v;
  __syncthreads();
  for (int d = 1; d < 256; d <<= 1) {
    int u = (t >= d) ? s[t - d] : 0;
    __syncthreads();
    s[t] += u;
    __syncthreads();
  }
  if (i < n) {
    int excl = bsum[blockIdx.x] + s[t] - v;
    rs[i] = excl;
    cur[i] = excl;
    isq[i] = rsqrtf((float)(v + 1));  // deg includes self-loop
  }
}

// ---------------- shared MFMA GEMM body (f16-split-x3, isq prescale) ----------

template <int K, int C>
__device__ __forceinline__ void gemm_body(const float* __restrict__ A,
                                          const _Float16* __restrict__ Wf,
                                          const float* __restrict__ isq,
                                          float* __restrict__ out, int n,
                                          _Float16* Wl, int blk) {
  constexpr int NK = K / 32, NCT = C / 16;
  constexpr int WH = NK * NCT * 2 * 512;
  int t = threadIdx.x;
  for (int i = t; i < WH / 8; i += 256)
    ((uint4*)Wl)[i] = ((const uint4*)Wf)[i];
  __syncthreads();

  int lane = t & 63, w = t >> 6;
  int rowbase = blk * 128 + w * 32;
  int ar0 = rowbase + (lane & 15);
  int kg = (lane >> 4) * 8;

  floatx4 acc[2][NCT];
#pragma unroll
  for (int g = 0; g < 2; ++g)
#pragma unroll
    for (int ct = 0; ct < NCT; ++ct) acc[g][ct] = (floatx4){0.f, 0.f, 0.f, 0.f};

  for (int ks = 0; ks < NK; ++ks) {
    half8 ah[2], al[2];
#pragma unroll
    for (int g = 0; g < 2; ++g) {
      int row = ar0 + g * 16;
      if (row > n - 1) row = n - 1;  // clamp: stores are guarded
      const float* ap = A + (size_t)row * K + ks * 32 + kg;
      float4 u0 = ((const float4*)ap)[0];
      float4 u1 = ((const float4*)ap)[1];
      float av[8] = {u0.x, u0.y, u0.z, u0.w, u1.x, u1.y, u1.z, u1.w};
#pragma unroll
      for (int q = 0; q < 8; ++q) {
        _Float16 h = (_Float16)av[q];
        ah[g][q] = h;
        al[g][q] = (_Float16)(av[q] - (float)h);
      }
    }
#pragma unroll
    for (int ct = 0; ct < NCT; ++ct) {
      const _Float16* bp = &Wl[((ks * NCT + ct) * 2) * 512 + lane * 8];
      half8 bh = *(const half8*)bp;
      half8 bl = *(const half8*)(bp + 512);
#pragma unroll
      for (int g = 0; g < 2; ++g) {
        acc[g][ct] = __builtin_amdgcn_mfma_f32_16x16x32_f16(ah[g], bh, acc[g][ct], 0, 0, 0);
        acc[g][ct] = __builtin_amdgcn_mfma_f32_16x16x32_f16(ah[g], bl, acc[g][ct], 0, 0, 0);
        acc[g][ct] = __builtin_amdgcn_mfma_f32_16x16x32_f16(al[g], bh, acc[g][ct], 0, 0, 0);
      }
    }
  }
  int drbase = rowbase + (lane >> 4) * 4;
  int col = lane & 15;
#pragma unroll
  for (int g = 0; g < 2; ++g)
#pragma unroll
    for (int r = 0; r < 4; ++r) {
      int row = drbase + g * 16 + r;
      if (row < n) {
        float s = isq[row];  // prescale: out row = isq[row] * (A@W)[row]
#pragma unroll
        for (int ct = 0; ct < NCT; ++ct)
          out[(size_t)row * C + ct * 16 + col] = acc[g][ct][r] * s;
      }
    }
}

template <int K, int C>
__global__ __launch_bounds__(256) void k_gemm_mfma(const float* __restrict__ A,
                                                   const _Float16* __restrict__ Wf,
                                                   const float* __restrict__ isq,
                                                   float* __restrict__ out, int n) {
  constexpr int WH = (K / 32) * (C / 16) * 2 * 512;
  __shared__ __align__(16) _Float16 Wl[WH];
  gemm_body<K, C>(A, Wf, isq, out, n, Wl, blockIdx.x);
}

// ---------------- fused csr-fill + gemm1 (independent work) ----------------

__global__ __launch_bounds__(256) void k_fill_gemm1(
    const float* __restrict__ A, const _Float16* __restrict__ Wf,
    const float* __restrict__ isq, float* __restrict__ out, int n,
    const int* __restrict__ ei, int E, int* __restrict__ cur,
    int* __restrict__ csr, int GT) {
  __shared__ __align__(16) _Float16 Wl[4 * 8 * 2 * 512];  // 64 KB (K=128,C=128)
  if (blockIdx.x >= GT) {
    int e = (blockIdx.x - GT) * 256 + threadIdx.x;
    if (e < E) {
      int s = __builtin_nontemporal_load(ei + e);
      int d = __builtin_nontemporal_load(ei + E + e);
      int pos = atomicAdd(&cur[d], 1);
      __builtin_nontemporal_store(s, csr + pos);
    }
    return;
  }
  gemm_body<128, 128>(A, Wf, isq, out, n, Wl, blockIdx.x);
}

// ---------------- CSR pull aggregation (prescaled rows, 4B csr) ----------------
// out[i] = isq[i]*(sum_e xs[src] + xs[i]) + b  (+relu);  xs = isq-prescaled.
// C=128: half-wave per edge (32 lanes x float4 = 512B row), 8 edges in flight.

template <bool RELU>
__global__ __launch_bounds__(256) void k_agg128(const float* __restrict__ xw,
                                                const int* __restrict__ rs,
                                                const int* __restrict__ csr,
                                                const float* __restrict__ isq,
                                                const float* __restrict__ bias,
                                                float* __restrict__ out, int n) {
  int gw = (int)((blockIdx.x * blockDim.x + threadIdx.x) >> 6);
  int lane = threadIdx.x & 63;
  if (gw >= n) return;
  int e0 = rs[gw], e1 = rs[gw + 1];
  int half = lane >> 5, sub = lane & 31;
  float4 acc = make_float4(0.f, 0.f, 0.f, 0.f);
  int e = e0 + half;
  for (; e + 6 < e1; e += 8) {
    int a = __builtin_nontemporal_load(csr + e);
    int b = __builtin_nontemporal_load(csr + e + 2);
    int c = __builtin_nontemporal_load(csr + e + 4);
    int d = __builtin_nontemporal_load(csr + e + 6);
    float4 va = *(const float4*)&xw[(size_t)a * 128 + 4 * sub];
    float4 vb = *(const float4*)&xw[(size_t)b * 128 + 4 * sub];
    float4 vc = *(const float4*)&xw[(size_t)c * 128 + 4 * sub];
    float4 vd = *(const float4*)&xw[(size_t)d * 128 + 4 * sub];
    acc.x += va.x + vb.x + vc.x + vd.x;
    acc.y += va.y + vb.y + vc.y + vd.y;
    acc.z += va.z + vb.z + vc.z + vd.z;
    acc.w += va.w + vb.w + vc.w + vd.w;
  }
  for (; e < e1; e += 2) {
    int a = __builtin_nontemporal_load(csr + e);
    float4 va = *(const float4*)&xw[(size_t)a * 128 + 4 * sub];
    acc.x += va.x;
    acc.y += va.y;
    acc.z += va.z;
    acc.w += va.w;
  }
  acc.x += __shfl_xor(acc.x, 32, 64);
  acc.y += __shfl_xor(acc.y, 32, 64);
  acc.z += __shfl_xor(acc.z, 32, 64);
  acc.w += __shfl_xor(acc.w, 32, 64);
  if (half == 0) {
    float qi = isq[gw];
    float4 self = *(const float4*)&xw[(size_t)gw * 128 + 4 * sub];
    float4 bv = *(const float4*)&bias[4 * sub];
    float4 r;
    r.x = qi * (acc.x + self.x) + bv.x;
    r.y = qi * (acc.y + self.y) + bv.y;
    r.z = qi * (acc.z + self.z) + bv.z;
    r.w = qi * (acc.w + self.w) + bv.w;
    if (RELU) {
      r.x = fmaxf(r.x, 0.f); r.y = fmaxf(r.y, 0.f);
      r.z = fmaxf(r.z, 0.f); r.w = fmaxf(r.w, 0.f);
    }
    *(float4*)&out[(size_t)gw * 128 + 4 * sub] = r;
  }
}

// C=64: quarter-wave per edge (16 lanes x float4 = 256B row), 16 edges in flight.

template <bool RELU>
__global__ __launch_bounds__(256) void k_agg64(const float* __restrict__ xw,
                                               const int* __restrict__ rs,
                                               const int* __restrict__ csr,
                                               const float* __restrict__ isq,
                                               const float* __restrict__ bias,
                                               float* __restrict__ out, int n) {
  int gw = (int)((blockIdx.x * blockDim.x + threadIdx.x) >> 6);
  int lane = threadIdx.x & 63;
  if (gw >= n) return;
  int e0 = rs[gw], e1 = rs[gw + 1];
  int qtr = lane >> 4, sub = lane & 15;
  float4 acc = make_float4(0.f, 0.f, 0.f, 0.f);
  int e = e0 + qtr;
  for (; e + 12 < e1; e += 16) {
    int a = __builtin_nontemporal_load(csr + e);
    int b = __builtin_nontemporal_load(csr + e + 4);
    int c = __builtin_nontemporal_load(csr + e + 8);
    int d = __builtin_nontemporal_load(csr + e + 12);
    float4 va = *(const float4*)&xw[(size_t)a * 64 + 4 * sub];
    float4 vb = *(const float4*)&xw[(size_t)b * 64 + 4 * sub];
    float4 vc = *(const float4*)&xw[(size_t)c * 64 + 4 * sub];
    float4 vd = *(const float4*)&xw[(size_t)d * 64 + 4 * sub];
    acc.x += va.x + vb.x + vc.x + vd.x;
    acc.y += va.y + vb.y + vc.y + vd.y;
    acc.z += va.z + vb.z + vc.z + vd.z;
    acc.w += va.w + vb.w + vc.w + vd.w;
  }
  for (; e < e1; e += 4) {
    int a = __builtin_nontemporal_load(csr + e);
    float4 va = *(const float4*)&xw[(size_t)a * 64 + 4 * sub];
    acc.x += va.x;
    acc.y += va.y;
    acc.z += va.z;
    acc.w += va.w;
  }
  acc.x += __shfl_xor(acc.x, 32, 64);
  acc.y += __shfl_xor(acc.y, 32, 64);
  acc.z += __shfl_xor(acc.z, 32, 64);
  acc.w += __shfl_xor(acc.w, 32, 64);
  acc.x += __shfl_xor(acc.x, 16, 64);
  acc.y += __shfl_xor(acc.y, 16, 64);
  acc.z += __shfl_xor(acc.z, 16, 64);
  acc.w += __shfl_xor(acc.w, 16, 64);
  if (qtr == 0) {
    float qi = isq[gw];
    float4 self = *(const float4*)&xw[(size_t)gw * 64 + 4 * sub];
    float4 bv = *(const float4*)&bias[4 * sub];
    float4 r;
    r.x = qi * (acc.x + self.x) + bv.x;
    r.y = qi * (acc.y + self.y) + bv.y;
    r.z = qi * (acc.z + self.z) + bv.z;
    r.w = qi * (acc.w + self.w) + bv.w;
    if (RELU) {
      r.x = fmaxf(r.x, 0.f); r.y = fmaxf(r.y, 0.f);
      r.z = fmaxf(r.z, 0.f); r.w = fmaxf(r.w, 0.f);
    }
    *(float4*)&out[(size_t)gw * 64 + 4 * sub] = r;
  }
}

// ---------------- fused link MLP ----------------

__global__ __launch_bounds__(256) void k_mlp(const float* __restrict__ z,
                                             const int* __restrict__ eli, int nlab,
                                             const float* __restrict__ Wl1,
                                             const float* __restrict__ bl1,
                                             const float* __restrict__ Wl2,
                                             const float* __restrict__ bl2,
                                             float* __restrict__ out) {
  constexpr int K = 128, TM = 4, LDA = K + 4;
  __shared__ float Wl[K * 64];
  __shared__ float Al[64 * LDA];
  int t = threadIdx.x;
  for (int i = t; i < K * 64 / 4; i += 256)
    ((float4*)Wl)[i] = ((const float4*)Wl1)[i];
  int rowbase = blockIdx.x * 64;
  {
    int r = t >> 2, p = t & 3;  // 4 threads/row; p<2 -> z[s], p>=2 -> z[d]
    int row = rowbase + r;
    int idx = 0;
    if (row < nlab) idx = (p < 2) ? eli[row] : eli[nlab + row];
    const float4* src = (const float4*)(z + (size_t)idx * 64);
    int srcq = (p & 1) * 8;
    int dst = r * LDA + (p >= 2 ? 64 : 0) + (p & 1) * 32;
#pragma unroll
    for (int q = 0; q < 8; ++q)
      *(float4*)&Al[dst + 4 * q] = src[srcq + q];
  }
  __syncthreads();
  int tx = t & 15, ty = t >> 4;
  float acc[TM][4] = {};
  for (int k = 0; k < K; ++k) {
    float a[TM];
#pragma unroll
    for (int i = 0; i < TM; ++i) a[i] = Al[(ty * TM + i) * LDA + k];
    float4 w = *(const float4*)&Wl[k * 64 + tx * 4];
#pragma unroll
    for (int i = 0; i < TM; ++i) {
      acc[i][0] += a[i] * w.x;
      acc[i][1] += a[i] * w.y;
      acc[i][2] += a[i] * w.z;
      acc[i][3] += a[i] * w.w;
    }
  }
  float4 b1v = *(const float4*)&bl1[tx * 4];
  float4 w2v = *(const float4*)&Wl2[tx * 4];
  float bias2 = bl2[0];
  float part[TM];
#pragma unroll
  for (int i = 0; i < TM; ++i) {
    float h0 = fmaxf(acc[i][0] + b1v.x, 0.f);
    float h1 = fmaxf(acc[i][1] + b1v.y, 0.f);
    float h2 = fmaxf(acc[i][2] + b1v.z, 0.f);
    float h3 = fmaxf(acc[i][3] + b1v.w, 0.f);
    part[i] = h0 * w2v.x + h1 * w2v.y + h2 * w2v.z + h3 * w2v.w;
  }
#pragma unroll
  for (int i = 0; i < TM; ++i) {
#pragma unroll
    for (int m = 1; m < 16; m <<= 1)
      part[i] += __shfl_xor(part[i], m, 64);
  }
  if (tx == 0) {
#pragma unroll
    for (int i = 0; i < TM; ++i) {
      int row = rowbase + ty * TM + i;
      if (row < nlab) out[row] = part[i] + bias2;
    }
  }
}

// ---------------- launcher ----------------

extern "C" void kernel_launch(void* const* d_in, const int* in_sizes, int n_in,
                              void* d_out, int out_size, void* d_ws, size_t ws_size,
                              hipStream_t stream) {
  const float* x   = (const float*)d_in[0];
  const int*   ei  = (const int*)d_in[1];
  const int*   eli = (const int*)d_in[2];
  const float* W1  = (const float*)d_in[3];
  const float* b1  = (const float*)d_in[4];
  const float* W2  = (const float*)d_in[5];
  const float* b2  = (const float*)d_in[6];
  const float* W3  = (const float*)d_in[7];
  const float* b3  = (const float*)d_in[8];
  const float* Wl1 = (const float*)d_in[9];
  const float* bl1 = (const float*)d_in[10];
  const float* Wl2 = (const float*)d_in[11];
  const float* bl2 = (const float*)d_in[12];
  float* out = (float*)d_out;
  const int n    = in_sizes[0] / 128;
  const int E    = in_sizes[1] / 2;
  const int nlab = in_sizes[2] / 2;
  (void)n_in; (void)out_size; (void)ws_size;

  char* ws = (char*)d_ws;
  size_t off = 0;
  auto alloc = [&](size_t bytes) -> void* {
    void* p = ws + off;
    off = (off + bytes + 255) & ~(size_t)255;
    return p;
  };
  float*     bufA = (float*)alloc((size_t)n * 128 * 4);
  float*     bufB = (float*)alloc((size_t)n * 128 * 4);
  int*       csr  = (int*)alloc((size_t)E * 4);
  int*       cnt  = (int*)alloc((size_t)n * 4);
  float*     isq  = (float*)alloc((size_t)n * 4);
  int*       rs   = (int*)alloc((size_t)(n + 1) * 4);
  int*       cur  = (int*)alloc((size_t)n * 4);
  const int  nb   = (n + 255) / 256;  // 391 for n=100000 (<=512 for k_scan2)
  int*       bsum = (int*)alloc((size_t)nb * 4);
  _Float16*  Wf1  = (_Float16*)alloc(128 * 128 * 2 * 2);
  _Float16*  Wf2  = (_Float16*)alloc(128 * 64 * 2 * 2);
  _Float16*  Wf3  = (_Float16*)alloc(64 * 64 * 2 * 2);

  const int HB = (E + 255) / 256;        // 6250 hist blocks
  const int GT = (n + 127) / 128;        // 782 gemm tiles
  const int aggb = (n + 3) / 4;          // 4 waves (nodes) per 256-thread block

  hipMemsetAsync(cnt, 0, (size_t)n * 4, stream);
  k_hist_wsplit<<<HB + 112, 256, 0, stream>>>(ei, E, cnt, W1, Wf1, W2, Wf2, W3, Wf3, HB);
  k_scan1<<<nb, 256, 0, stream>>>(cnt, bsum, n);
  k_scan2<<<1, 512, 0, stream>>>(bsum, nb, rs, n);
  k_scan3<<<nb, 256, 0, stream>>>(cnt, bsum, rs, cur, isq, n);

  // gemm1 (prescaled xs1 = isq .* x@W1) fused with csr fill (independent).
  k_fill_gemm1<<<GT + HB, 256, 0, stream>>>(x, Wf1, isq, bufA, n, ei, E, cur, csr, GT);
  k_agg128<true><<<aggb, 256, 0, stream>>>(bufA, rs, csr, isq, b1, bufB, n);
  k_gemm_mfma<128, 64><<<GT, 256, 0, stream>>>(bufB, Wf2, isq, bufA, n);
  k_agg64<true><<<aggb, 256, 0, stream>>>(bufA, rs, csr, isq, b2, bufB, n);
  k_gemm_mfma<64, 64><<<GT, 256, 0, stream>>>(bufB, Wf3, isq, bufA, n);
  k_agg64<false><<<aggb, 256, 0, stream>>>(bufA, rs, csr, isq, b3, bufB, n);
  k_mlp<<<(nlab + 63) / 64, 256, 0, stream>>>(bufB, eli, nlab, Wl1, bl1, Wl2, bl2, out);
}

// Round 5
// 417.846 us; speedup vs baseline: 1.6569x; 1.2653x over previous
//
#include <hip/hip_runtime.h>

// GCN link predictor, MI355X (gfx950).
// Round 5: (a) fill unfused from gemm1; (b) hist & fill are XCD-role-split
// (blockIdx&7 -> dst-range partition; scatter windows stay L2-local, edge list
// re-read 8x from L3); (c) GEMM outputs (prescaled xs = isq .* h@W) stored f16,
// halving the dominant agg gather traffic. z stays f32 (GEMM A + MLP inputs).

typedef _Float16 half8 __attribute__((ext_vector_type(8)));
typedef float floatx4 __attribute__((ext_vector_type(4)));

#define EPB 8          // edges per thread in role-split hist/fill
#define CHUNK (256 * EPB)

// ---------------- fused role-split hist + weight split ----------------
// blocks [0, 8*CH): histogram of dst, XCD-role-split.
// blocks [8*CH, +112): f32->f16 hi/lo split of W1/W2/W3 into MFMA B-frag layout.

__global__ __launch_bounds__(256) void k_hist_wsplit(
    const int* __restrict__ ei, int E, int n, int* __restrict__ cnt,
    const float* __restrict__ W1, _Float16* __restrict__ Wf1,
    const float* __restrict__ W2, _Float16* __restrict__ Wf2,
    const float* __restrict__ W3, _Float16* __restrict__ Wf3, int HB) {
  int b = blockIdx.x;
  if (b < HB) {
    int role = b & 7, chunk = b >> 3;
    int ns = (n + 7) / 8;
    int lo = role * ns, hi = min(n, lo + ns);
    int e0 = chunk * CHUNK + threadIdx.x;
#pragma unroll
    for (int q = 0; q < EPB; ++q) {
      int e = e0 + q * 256;
      if (e < E) {
        int d = __builtin_nontemporal_load(ei + E + e);
        if (d >= lo && d < hi) atomicAdd(&cnt[d], 1);
      }
    }
    return;
  }
  b -= HB;
  const float* W;
  _Float16* Wf;
  int KC, lc;
  if (b < 64)      { W = W1; Wf = Wf1; KC = 16384; lc = 7; }
  else if (b < 96) { b -= 64; W = W2; Wf = Wf2; KC = 8192; lc = 6; }
  else             { b -= 96; W = W3; Wf = Wf3; KC = 4096; lc = 6; }
  int t = b * 256 + threadIdx.x;
  if (t >= KC) return;
  int C = 1 << lc;
  int c = t & (C - 1), k = t >> lc;
  float a = W[t];
  _Float16 h = (_Float16)a;
  _Float16 l = (_Float16)(a - (float)h);
  int ks = k >> 5, ct = c >> 4;
  int lane = ((k & 31) >> 3) * 16 + (c & 15);
  int j = k & 7;
  int base = ((ks * (C >> 4) + ct) * 2) * 512 + lane * 8 + j;
  Wf[base] = h;
  Wf[base + 512] = l;
}

// ---------------- scans ----------------

__global__ void k_scan1(const int* __restrict__ cnt, int* __restrict__ bsum, int n) {
  __shared__ int s[256];
  int i = blockIdx.x * 256 + threadIdx.x;
  int t = threadIdx.x;
  s[t] = (i < n) ? cnt[i] : 0;
  __syncthreads();
  for (int d = 128; d > 0; d >>= 1) {
    if (t < d) s[t] += s[t + d];
    __syncthreads();
  }
  if (t == 0) bsum[blockIdx.x] = s[0];
}

__global__ void k_scan2(int* __restrict__ bsum, int m, int* __restrict__ rs, int n) {
  __shared__ int s[512];
  int t = threadIdx.x;
  s[t] = (t < m) ? bsum[t] : 0;
  __syncthreads();
  for (int d = 1; d < 512; d <<= 1) {
    int v = (t >= d) ? s[t - d] : 0;
    __syncthreads();
    s[t] += v;
    __syncthreads();
  }
  if (t < m) bsum[t] = t ? s[t - 1] : 0;
  if (t == m - 1) rs[n] = s[t];
}

__global__ void k_scan3(const int* __restrict__ cnt, const int* __restrict__ bsum,
                        int* __restrict__ rs, int* __restrict__ cur,
                        float* __restrict__ isq, int n) {
  __shared__ int s[256];
  int i = blockIdx.x * 256 + threadIdx.x;
  int t = threadIdx.x;
  int v = (i < n) ? cnt[i] : 0;
  s[t] = v;
  __syncthreads();
  for (int d = 1; d < 256; d <<= 1) {
    int u = (t >= d) ? s[t - d] : 0;
    __syncthreads();
    s[t] += u;
    __syncthreads();
  }
  if (i < n) {
    int excl = bsum[blockIdx.x] + s[t] - v;
    rs[i] = excl;
    cur[i] = excl;
    isq[i] = rsqrtf((float)(v + 1));  // deg includes self-loop
  }
}

// ---------------- XCD-role-split CSR fill ----------------

__global__ __launch_bounds__(256) void k_fill(const int* __restrict__ ei, int E,
                                              int n, int* __restrict__ cur,
                                              int* __restrict__ csr) {
  int role = blockIdx.x & 7, chunk = blockIdx.x >> 3;
  int ns = (n + 7) / 8;
  int lo = role * ns, hi = min(n, lo + ns);
  int e0 = chunk * CHUNK + threadIdx.x;
#pragma unroll
  for (int q = 0; q < EPB; ++q) {
    int e = e0 + q * 256;
    if (e < E) {
      int s = __builtin_nontemporal_load(ei + e);
      int d = __builtin_nontemporal_load(ei + E + e);
      if (d >= lo && d < hi) {
        int pos = atomicAdd(&cur[d], 1);
        csr[pos] = s;
      }
    }
  }
}

// ---------------- MFMA GEMM: xs[n,C] = isq .* (A[n,K] @ W[K,C]), f16 out -----

template <int K, int C>
__global__ __launch_bounds__(256) void k_gemm_mfma(const float* __restrict__ A,
                                                   const _Float16* __restrict__ Wf,
                                                   const float* __restrict__ isq,
                                                   _Float16* __restrict__ out, int n) {
  constexpr int NK = K / 32, NCT = C / 16;
  constexpr int WH = NK * NCT * 2 * 512;
  __shared__ __align__(16) _Float16 Wl[WH];
  int t = threadIdx.x;
  for (int i = t; i < WH / 8; i += 256)
    ((uint4*)Wl)[i] = ((const uint4*)Wf)[i];
  __syncthreads();

  int lane = t & 63, w = t >> 6;
  int rowbase = blockIdx.x * 128 + w * 32;
  int ar0 = rowbase + (lane & 15);
  int kg = (lane >> 4) * 8;

  floatx4 acc[2][NCT];
#pragma unroll
  for (int g = 0; g < 2; ++g)
#pragma unroll
    for (int ct = 0; ct < NCT; ++ct) acc[g][ct] = (floatx4){0.f, 0.f, 0.f, 0.f};

  for (int ks = 0; ks < NK; ++ks) {
    half8 ah[2], al[2];
#pragma unroll
    for (int g = 0; g < 2; ++g) {
      int row = ar0 + g * 16;
      if (row > n - 1) row = n - 1;  // clamp: stores are guarded
      const float* ap = A + (size_t)row * K + ks * 32 + kg;
      float4 u0 = ((const float4*)ap)[0];
      float4 u1 = ((const float4*)ap)[1];
      float av[8] = {u0.x, u0.y, u0.z, u0.w, u1.x, u1.y, u1.z, u1.w};
#pragma unroll
      for (int q = 0; q < 8; ++q) {
        _Float16 h = (_Float16)av[q];
        ah[g][q] = h;
        al[g][q] = (_Float16)(av[q] - (float)h);
      }
    }
#pragma unroll
    for (int ct = 0; ct < NCT; ++ct) {
      const _Float16* bp = &Wl[((ks * NCT + ct) * 2) * 512 + lane * 8];
      half8 bh = *(const half8*)bp;
      half8 bl = *(const half8*)(bp + 512);
#pragma unroll
      for (int g = 0; g < 2; ++g) {
        acc[g][ct] = __builtin_amdgcn_mfma_f32_16x16x32_f16(ah[g], bh, acc[g][ct], 0, 0, 0);
        acc[g][ct] = __builtin_amdgcn_mfma_f32_16x16x32_f16(ah[g], bl, acc[g][ct], 0, 0, 0);
        acc[g][ct] = __builtin_amdgcn_mfma_f32_16x16x32_f16(al[g], bh, acc[g][ct], 0, 0, 0);
      }
    }
  }
  int drbase = rowbase + (lane >> 4) * 4;
  int col = lane & 15;
#pragma unroll
  for (int g = 0; g < 2; ++g)
#pragma unroll
    for (int r = 0; r < 4; ++r) {
      int row = drbase + g * 16 + r;
      if (row < n) {
        float s = isq[row];  // prescale: xs row = isq[row] * (A@W)[row]
#pragma unroll
        for (int ct = 0; ct < NCT; ++ct)
          out[(size_t)row * C + ct * 16 + col] = (_Float16)(acc[g][ct][r] * s);
      }
    }
}

// ---------------- CSR pull aggregation over f16 xs tables ----------------
// z[i] = isq[i]*(sum_e xs[src] + xs[i]) + b  (+relu), accumulated f32, z f32.
// C=128: quarter-wave per edge (16 lanes x half8 = 256B row), 16 in flight.

template <bool RELU>
__global__ __launch_bounds__(256) void k_agg128(const _Float16* __restrict__ xs,
                                                const int* __restrict__ rs,
                                                const int* __restrict__ csr,
                                                const float* __restrict__ isq,
                                                const float* __restrict__ bias,
                                                float* __restrict__ out, int n) {
  int gw = (int)((blockIdx.x * blockDim.x + threadIdx.x) >> 6);
  int lane = threadIdx.x & 63;
  if (gw >= n) return;
  int e0 = rs[gw], e1 = rs[gw + 1];
  int qtr = lane >> 4, sub = lane & 15;
  float acc[8] = {};
  int e = e0 + qtr;
  for (; e + 12 < e1; e += 16) {
    int a = __builtin_nontemporal_load(csr + e);
    int b = __builtin_nontemporal_load(csr + e + 4);
    int c = __builtin_nontemporal_load(csr + e + 8);
    int d = __builtin_nontemporal_load(csr + e + 12);
    half8 va = *(const half8*)&xs[(size_t)a * 128 + 8 * sub];
    half8 vb = *(const half8*)&xs[(size_t)b * 128 + 8 * sub];
    half8 vc = *(const half8*)&xs[(size_t)c * 128 + 8 * sub];
    half8 vd = *(const half8*)&xs[(size_t)d * 128 + 8 * sub];
#pragma unroll
    for (int j = 0; j < 8; ++j)
      acc[j] += (float)va[j] + (float)vb[j] + (float)vc[j] + (float)vd[j];
  }
  for (; e < e1; e += 4) {
    int a = __builtin_nontemporal_load(csr + e);
    half8 va = *(const half8*)&xs[(size_t)a * 128 + 8 * sub];
#pragma unroll
    for (int j = 0; j < 8; ++j) acc[j] += (float)va[j];
  }
#pragma unroll
  for (int j = 0; j < 8; ++j) {
    acc[j] += __shfl_xor(acc[j], 32, 64);
    acc[j] += __shfl_xor(acc[j], 16, 64);
  }
  if (qtr == 0) {
    float qi = isq[gw];
    half8 self = *(const half8*)&xs[(size_t)gw * 128 + 8 * sub];
#pragma unroll
    for (int j = 0; j < 8; ++j) {
      float r = qi * (acc[j] + (float)self[j]) + bias[8 * sub + j];
      if (RELU) r = fmaxf(r, 0.f);
      out[(size_t)gw * 128 + 8 * sub + j] = r;
    }
  }
}

// C=64: eighth-wave per edge (8 lanes x half8 = 128B row), 16 in flight.

template <bool RELU>
__global__ __launch_bounds__(256) void k_agg64(const _Float16* __restrict__ xs,
                                               const int* __restrict__ rs,
                                               const int* __restrict__ csr,
                                               const float* __restrict__ isq,
                                               const float* __restrict__ bias,
                                               float* __restrict__ out, int n) {
  int gw = (int)((blockIdx.x * blockDim.x + threadIdx.x) >> 6);
  int lane = threadIdx.x & 63;
  if (gw >= n) return;
  int e0 = rs[gw], e1 = rs[gw + 1];
  int oct = lane >> 3, sub = lane & 7;
  float acc[8] = {};
  int e = e0 + oct;
  for (; e + 8 < e1; e += 16) {
    int a = __builtin_nontemporal_load(csr + e);
    int b = __builtin_nontemporal_load(csr + e + 8);
    half8 va = *(const half8*)&xs[(size_t)a * 64 + 8 * sub];
    half8 vb = *(const half8*)&xs[(size_t)b * 64 + 8 * sub];
#pragma unroll
    for (int j = 0; j < 8; ++j) acc[j] += (float)va[j] + (float)vb[j];
  }
  for (; e < e1; e += 8) {
    int a = __builtin_nontemporal_load(csr + e);
    half8 va = *(const half8*)&xs[(size_t)a * 64 + 8 * sub];
#pragma unroll
    for (int j = 0; j < 8; ++j) acc[j] += (float)va[j];
  }
#pragma unroll
  for (int j = 0; j < 8; ++j) {
    acc[j] += __shfl_xor(acc[j], 32, 64);
    acc[j] += __shfl_xor(acc[j], 16, 64);
    acc[j] += __shfl_xor(acc[j], 8, 64);
  }
  if (oct == 0) {
    float qi = isq[gw];
    half8 self = *(const half8*)&xs[(size_t)gw * 64 + 8 * sub];
#pragma unroll
    for (int j = 0; j < 8; ++j) {
      float r = qi * (acc[j] + (float)self[j]) + bias[8 * sub + j];
      if (RELU) r = fmaxf(r, 0.f);
      out[(size_t)gw * 64 + 8 * sub + j] = r;
    }
  }
}

// ---------------- fused link MLP ----------------

__global__ __launch_bounds__(256) void k_mlp(const float* __restrict__ z,
                                             const int* __restrict__ eli, int nlab,
                                             const float* __restrict__ Wl1,
                                             const float* __restrict__ bl1,
                                             const float* __restrict__ Wl2,
                                             const float* __restrict__ bl2,
                                             float* __restrict__ out) {
  constexpr int K = 128, TM = 4, LDA = K + 4;
  __shared__ float Wl[K * 64];
  __shared__ float Al[64 * LDA];
  int t = threadIdx.x;
  for (int i = t; i < K * 64 / 4; i += 256)
    ((float4*)Wl)[i] = ((const float4*)Wl1)[i];
  int rowbase = blockIdx.x * 64;
  {
    int r = t >> 2, p = t & 3;  // 4 threads/row; p<2 -> z[s], p>=2 -> z[d]
    int row = rowbase + r;
    int idx = 0;
    if (row < nlab) idx = (p < 2) ? eli[row] : eli[nlab + row];
    const float4* src = (const float4*)(z + (size_t)idx * 64);
    int srcq = (p & 1) * 8;
    int dst = r * LDA + (p >= 2 ? 64 : 0) + (p & 1) * 32;
#pragma unroll
    for (int q = 0; q < 8; ++q)
      *(float4*)&Al[dst + 4 * q] = src[srcq + q];
  }
  __syncthreads();
  int tx = t & 15, ty = t >> 4;
  float acc[TM][4] = {};
  for (int k = 0; k < K; ++k) {
    float a[TM];
#pragma unroll
    for (int i = 0; i < TM; ++i) a[i] = Al[(ty * TM + i) * LDA + k];
    float4 w = *(const float4*)&Wl[k * 64 + tx * 4];
#pragma unroll
    for (int i = 0; i < TM; ++i) {
      acc[i][0] += a[i] * w.x;
      acc[i][1] += a[i] * w.y;
      acc[i][2] += a[i] * w.z;
      acc[i][3] += a[i] * w.w;
    }
  }
  float4 b1v = *(const float4*)&bl1[tx * 4];
  float4 w2v = *(const float4*)&Wl2[tx * 4];
  float bias2 = bl2[0];
  float part[TM];
#pragma unroll
  for (int i = 0; i < TM; ++i) {
    float h0 = fmaxf(acc[i][0] + b1v.x, 0.f);
    float h1 = fmaxf(acc[i][1] + b1v.y, 0.f);
    float h2 = fmaxf(acc[i][2] + b1v.z, 0.f);
    float h3 = fmaxf(acc[i][3] + b1v.w, 0.f);
    part[i] = h0 * w2v.x + h1 * w2v.y + h2 * w2v.z + h3 * w2v.w;
  }
#pragma unroll
  for (int i = 0; i < TM; ++i) {
#pragma unroll
    for (int m = 1; m < 16; m <<= 1)
      part[i] += __shfl_xor(part[i], m, 64);
  }
  if (tx == 0) {
#pragma unroll
    for (int i = 0; i < TM; ++i) {
      int row = rowbase + ty * TM + i;
      if (row < nlab) out[row] = part[i] + bias2;
    }
  }
}

// ---------------- launcher ----------------

extern "C" void kernel_launch(void* const* d_in, const int* in_sizes, int n_in,
                              void* d_out, int out_size, void* d_ws, size_t ws_size,
                              hipStream_t stream) {
  const float* x   = (const float*)d_in[0];
  const int*   ei  = (const int*)d_in[1];
  const int*   eli = (const int*)d_in[2];
  const float* W1  = (const float*)d_in[3];
  const float* b1  = (const float*)d_in[4];
  const float* W2  = (const float*)d_in[5];
  const float* b2  = (const float*)d_in[6];
  const float* W3  = (const float*)d_in[7];
  const float* b3  = (const float*)d_in[8];
  const float* Wl1 = (const float*)d_in[9];
  const float* bl1 = (const float*)d_in[10];
  const float* Wl2 = (const float*)d_in[11];
  const float* bl2 = (const float*)d_in[12];
  float* out = (float*)d_out;
  const int n    = in_sizes[0] / 128;
  const int E    = in_sizes[1] / 2;
  const int nlab = in_sizes[2] / 2;
  (void)n_in; (void)out_size; (void)ws_size;

  char* ws = (char*)d_ws;
  size_t off = 0;
  auto alloc = [&](size_t bytes) -> void* {
    void* p = ws + off;
    off = (off + bytes + 255) & ~(size_t)255;
    return p;
  };
  float*     bufZ1 = (float*)alloc((size_t)n * 128 * 4);   // z1 (f32); reused for z3
  float*     bufZ2 = (float*)alloc((size_t)n * 64 * 4);    // z2 (f32)
  _Float16*  bufXS = (_Float16*)alloc((size_t)n * 128 * 2);// xs tables (f16)
  int*       csr   = (int*)alloc((size_t)E * 4);
  int*       cnt   = (int*)alloc((size_t)n * 4);
  float*     isq   = (float*)alloc((size_t)n * 4);
  int*       rs    = (int*)alloc((size_t)(n + 1) * 4);
  int*       cur   = (int*)alloc((size_t)n * 4);
  const int  nb    = (n + 255) / 256;  // 391 (<=512 for k_scan2)
  int*       bsum  = (int*)alloc((size_t)nb * 4);
  _Float16*  Wf1   = (_Float16*)alloc(128 * 128 * 2 * 2);
  _Float16*  Wf2   = (_Float16*)alloc(128 * 64 * 2 * 2);
  _Float16*  Wf3   = (_Float16*)alloc(64 * 64 * 2 * 2);
  float*     z3    = bufZ1;  // reuse (stride 64)

  const int CH  = (E + CHUNK - 1) / CHUNK;  // edge chunks (2048 edges each)
  const int HB  = 8 * CH;                   // role-split hist blocks
  const int GT  = (n + 127) / 128;          // gemm tiles
  const int aggb = (n + 3) / 4;             // 4 waves (nodes) per block

  hipMemsetAsync(cnt, 0, (size_t)n * 4, stream);
  k_hist_wsplit<<<HB + 112, 256, 0, stream>>>(ei, E, n, cnt, W1, Wf1, W2, Wf2, W3, Wf3, HB);
  k_scan1<<<nb, 256, 0, stream>>>(cnt, bsum, n);
  k_scan2<<<1, 512, 0, stream>>>(bsum, nb, rs, n);
  k_scan3<<<nb, 256, 0, stream>>>(cnt, bsum, rs, cur, isq, n);
  k_fill<<<HB, 256, 0, stream>>>(ei, E, n, cur, csr);

  k_gemm_mfma<128, 128><<<GT, 256, 0, stream>>>(x, Wf1, isq, bufXS, n);
  k_agg128<true><<<aggb, 256, 0, stream>>>(bufXS, rs, csr, isq, b1, bufZ1, n);
  k_gemm_mfma<128, 64><<<GT, 256, 0, stream>>>(bufZ1, Wf2, isq, bufXS, n);
  k_agg64<true><<<aggb, 256, 0, stream>>>(bufXS, rs, csr, isq, b2, bufZ2, n);
  k_gemm_mfma<64, 64><<<GT, 256, 0, stream>>>(bufZ2, Wf3, isq, bufXS, n);
  k_agg64<false><<<aggb, 256, 0, stream>>>(bufXS, rs, csr, isq, b3, z3, n);
  k_mlp<<<(nlab + 63) / 64, 256, 0, stream>>>(z3, eli, nlab, Wl1, bl1, Wl2, bl2, out);
}

// Round 6
// 395.164 us; speedup vs baseline: 1.7520x; 1.0574x over previous
//
#include <hip/hip_runtime.h>

// GCN link predictor, MI355X (gfx950).
// Round 6: rank-trick CSR build — k_hist's atomicAdd old-value IS the edge's
// rank within its dst; store rank[e] (ushort, coalesced). k_fill then has NO
// atomic: pos = rs[d] + rank[e] (pure loads + scattered store, role-split so
// the rs/csr windows stay XCD-L2-local). scan2 folded into scan3 (self-computed
// block offsets). GEMMs: f16-split-x3 MFMA with isq-prescale, f16 xs tables;
// aggs gather f16 rows (quarter-/eighth-wave per edge); fused link MLP.

typedef _Float16 half8 __attribute__((ext_vector_type(8)));
typedef float floatx4 __attribute__((ext_vector_type(4)));

#define EPB 8          // edges per thread in role-split hist/fill
#define CHUNK (256 * EPB)

// ---------------- fused role-split hist(+rank) + weight split ----------------
// blocks [0, HB): histogram of dst, XCD-role-split; rank[e] = old count.
// blocks [HB, HB+112): f32->f16 hi/lo split of W1/W2/W3 into MFMA B-frag layout.

__global__ __launch_bounds__(256) void k_hist_wsplit(
    const int* __restrict__ ei, int E, int n, int* __restrict__ cnt,
    unsigned short* __restrict__ rank,
    const float* __restrict__ W1, _Float16* __restrict__ Wf1,
    const float* __restrict__ W2, _Float16* __restrict__ Wf2,
    const float* __restrict__ W3, _Float16* __restrict__ Wf3, int HB) {
  int b = blockIdx.x;
  if (b < HB) {
    int role = b & 7, chunk = b >> 3;
    int ns = (n + 7) / 8;
    int lo = role * ns, hi = min(n, lo + ns);
    int e0 = chunk * CHUNK + threadIdx.x;
#pragma unroll
    for (int q = 0; q < EPB; ++q) {
      int e = e0 + q * 256;
      if (e < E) {
        int d = __builtin_nontemporal_load(ei + E + e);
        if (d >= lo && d < hi) {
          int r = atomicAdd(&cnt[d], 1);
          rank[e] = (unsigned short)r;
        }
      }
    }
    return;
  }
  b -= HB;
  const float* W;
  _Float16* Wf;
  int KC, lc;
  if (b < 64)      { W = W1; Wf = Wf1; KC = 16384; lc = 7; }
  else if (b < 96) { b -= 64; W = W2; Wf = Wf2; KC = 8192; lc = 6; }
  else             { b -= 96; W = W3; Wf = Wf3; KC = 4096; lc = 6; }
  int t = b * 256 + threadIdx.x;
  if (t >= KC) return;
  int C = 1 << lc;
  int c = t & (C - 1), k = t >> lc;
  float a = W[t];
  _Float16 h = (_Float16)a;
  _Float16 l = (_Float16)(a - (float)h);
  int ks = k >> 5, ct = c >> 4;
  int lane = ((k & 31) >> 3) * 16 + (c & 15);
  int j = k & 7;
  int base = ((ks * (C >> 4) + ct) * 2) * 512 + lane * 8 + j;
  Wf[base] = h;
  Wf[base + 512] = l;
}

// ---------------- scans (2 dispatches) ----------------

__global__ void k_scan1(const int* __restrict__ cnt, int* __restrict__ bsum, int n) {
  __shared__ int s[256];
  int i = blockIdx.x * 256 + threadIdx.x;
  int t = threadIdx.x;
  s[t] = (i < n) ? cnt[i] : 0;
  __syncthreads();
  for (int d = 128; d > 0; d >>= 1) {
    if (t < d) s[t] += s[t + d];
    __syncthreads();
  }
  if (t == 0) bsum[blockIdx.x] = s[0];
}

// Each block self-computes offset = sum(bsum[0..blockIdx)), then local exclusive
// scan of cnt; writes rs, isq; thread at i==n-1 writes rs[n].
__global__ void k_scan23(const int* __restrict__ cnt, const int* __restrict__ bsum,
                         int nb, int* __restrict__ rs, float* __restrict__ isq,
                         int n) {
  __shared__ int s[256];
  __shared__ int off;
  int t = threadIdx.x;
  int b = blockIdx.x;
  // ---- block offset: reduce bsum[0..b) ----
  int acc = 0;
  for (int j = t; j < b; j += 256) acc += bsum[j];
  s[t] = acc;
  __syncthreads();
  for (int d = 128; d > 0; d >>= 1) {
    if (t < d) s[t] += s[t + d];
    __syncthreads();
  }
  if (t == 0) off = s[0];
  __syncthreads();
  int blockoff = off;
  __syncthreads();
  // ---- local inclusive scan of cnt ----
  int i = b * 256 + t;
  int v = (i < n) ? cnt[i] : 0;
  s[t] = v;
  __syncthreads();
  for (int d = 1; d < 256; d <<= 1) {
    int u = (t >= d) ? s[t - d] : 0;
    __syncthreads();
    s[t] += u;
    __syncthreads();
  }
  if (i < n) {
    int excl = blockoff + s[t] - v;
    rs[i] = excl;
    isq[i] = rsqrtf((float)(v + 1));  // deg includes self-loop
    if (i == n - 1) rs[n] = excl + v;
  }
}

// ---------------- XCD-role-split atomic-free CSR fill ----------------

__global__ __launch_bounds__(256) void k_fill(const int* __restrict__ ei, int E,
                                              int n, const int* __restrict__ rs,
                                              const unsigned short* __restrict__ rank,
                                              int* __restrict__ csr) {
  int role = blockIdx.x & 7, chunk = blockIdx.x >> 3;
  int ns = (n + 7) / 8;
  int lo = role * ns, hi = min(n, lo + ns);
  int e0 = chunk * CHUNK + threadIdx.x;
#pragma unroll
  for (int q = 0; q < EPB; ++q) {
    int e = e0 + q * 256;
    if (e < E) {
      int d = __builtin_nontemporal_load(ei + E + e);
      if (d >= lo && d < hi) {
        int s = __builtin_nontemporal_load(ei + e);
        int r = __builtin_nontemporal_load(rank + e);
        csr[rs[d] + r] = s;
      }
    }
  }
}

// ---------------- MFMA GEMM: xs[n,C] = isq .* (A[n,K] @ W[K,C]), f16 out -----

template <int K, int C>
__global__ __launch_bounds__(256) void k_gemm_mfma(const float* __restrict__ A,
                                                   const _Float16* __restrict__ Wf,
                                                   const float* __restrict__ isq,
                                                   _Float16* __restrict__ out, int n) {
  constexpr int NK = K / 32, NCT = C / 16;
  constexpr int WH = NK * NCT * 2 * 512;
  __shared__ __align__(16) _Float16 Wl[WH];
  int t = threadIdx.x;
  for (int i = t; i < WH / 8; i += 256)
    ((uint4*)Wl)[i] = ((const uint4*)Wf)[i];
  __syncthreads();

  int lane = t & 63, w = t >> 6;
  int rowbase = blockIdx.x * 128 + w * 32;
  int ar0 = rowbase + (lane & 15);
  int kg = (lane >> 4) * 8;

  floatx4 acc[2][NCT];
#pragma unroll
  for (int g = 0; g < 2; ++g)
#pragma unroll
    for (int ct = 0; ct < NCT; ++ct) acc[g][ct] = (floatx4){0.f, 0.f, 0.f, 0.f};

  for (int ks = 0; ks < NK; ++ks) {
    half8 ah[2], al[2];
#pragma unroll
    for (int g = 0; g < 2; ++g) {
      int row = ar0 + g * 16;
      if (row > n - 1) row = n - 1;  // clamp: stores are guarded
      const float* ap = A + (size_t)row * K + ks * 32 + kg;
      float4 u0 = ((const float4*)ap)[0];
      float4 u1 = ((const float4*)ap)[1];
      float av[8] = {u0.x, u0.y, u0.z, u0.w, u1.x, u1.y, u1.z, u1.w};
#pragma unroll
      for (int q = 0; q < 8; ++q) {
        _Float16 h = (_Float16)av[q];
        ah[g][q] = h;
        al[g][q] = (_Float16)(av[q] - (float)h);
      }
    }
#pragma unroll
    for (int ct = 0; ct < NCT; ++ct) {
      const _Float16* bp = &Wl[((ks * NCT + ct) * 2) * 512 + lane * 8];
      half8 bh = *(const half8*)bp;
      half8 bl = *(const half8*)(bp + 512);
#pragma unroll
      for (int g = 0; g < 2; ++g) {
        acc[g][ct] = __builtin_amdgcn_mfma_f32_16x16x32_f16(ah[g], bh, acc[g][ct], 0, 0, 0);
        acc[g][ct] = __builtin_amdgcn_mfma_f32_16x16x32_f16(ah[g], bl, acc[g][ct], 0, 0, 0);
        acc[g][ct] = __builtin_amdgcn_mfma_f32_16x16x32_f16(al[g], bh, acc[g][ct], 0, 0, 0);
      }
    }
  }
  int drbase = rowbase + (lane >> 4) * 4;
  int col = lane & 15;
#pragma unroll
  for (int g = 0; g < 2; ++g)
#pragma unroll
    for (int r = 0; r < 4; ++r) {
      int row = drbase + g * 16 + r;
      if (row < n) {
        float s = isq[row];  // prescale: xs row = isq[row] * (A@W)[row]
#pragma unroll
        for (int ct = 0; ct < NCT; ++ct)
          out[(size_t)row * C + ct * 16 + col] = (_Float16)(acc[g][ct][r] * s);
      }
    }
}

// ---------------- CSR pull aggregation over f16 xs tables ----------------
// z[i] = isq[i]*(sum_e xs[src] + xs[i]) + b  (+relu), accumulated f32, z f32.
// C=128: quarter-wave per edge (16 lanes x half8 = 256B row), 16 in flight.

template <bool RELU>
__global__ __launch_bounds__(256) void k_agg128(const _Float16* __restrict__ xs,
                                                const int* __restrict__ rs,
                                                const int* __restrict__ csr,
                                                const float* __restrict__ isq,
                                                const float* __restrict__ bias,
                                                float* __restrict__ out, int n) {
  int gw = (int)((blockIdx.x * blockDim.x + threadIdx.x) >> 6);
  int lane = threadIdx.x & 63;
  if (gw >= n) return;
  int e0 = rs[gw], e1 = rs[gw + 1];
  int qtr = lane >> 4, sub = lane & 15;
  float acc[8] = {};
  int e = e0 + qtr;
  for (; e + 12 < e1; e += 16) {
    int a = __builtin_nontemporal_load(csr + e);
    int b = __builtin_nontemporal_load(csr + e + 4);
    int c = __builtin_nontemporal_load(csr + e + 8);
    int d = __builtin_nontemporal_load(csr + e + 12);
    half8 va = *(const half8*)&xs[(size_t)a * 128 + 8 * sub];
    half8 vb = *(const half8*)&xs[(size_t)b * 128 + 8 * sub];
    half8 vc = *(const half8*)&xs[(size_t)c * 128 + 8 * sub];
    half8 vd = *(const half8*)&xs[(size_t)d * 128 + 8 * sub];
#pragma unroll
    for (int j = 0; j < 8; ++j)
      acc[j] += (float)va[j] + (float)vb[j] + (float)vc[j] + (float)vd[j];
  }
  for (; e < e1; e += 4) {
    int a = __builtin_nontemporal_load(csr + e);
    half8 va = *(const half8*)&xs[(size_t)a * 128 + 8 * sub];
#pragma unroll
    for (int j = 0; j < 8; ++j) acc[j] += (float)va[j];
  }
#pragma unroll
  for (int j = 0; j < 8; ++j) {
    acc[j] += __shfl_xor(acc[j], 32, 64);
    acc[j] += __shfl_xor(acc[j], 16, 64);
  }
  if (qtr == 0) {
    float qi = isq[gw];
    half8 self = *(const half8*)&xs[(size_t)gw * 128 + 8 * sub];
#pragma unroll
    for (int j = 0; j < 8; ++j) {
      float r = qi * (acc[j] + (float)self[j]) + bias[8 * sub + j];
      if (RELU) r = fmaxf(r, 0.f);
      out[(size_t)gw * 128 + 8 * sub + j] = r;
    }
  }
}

// C=64: eighth-wave per edge (8 lanes x half8 = 128B row), 16 in flight.

template <bool RELU>
__global__ __launch_bounds__(256) void k_agg64(const _Float16* __restrict__ xs,
                                               const int* __restrict__ rs,
                                               const int* __restrict__ csr,
                                               const float* __restrict__ isq,
                                               const float* __restrict__ bias,
                                               float* __restrict__ out, int n) {
  int gw = (int)((blockIdx.x * blockDim.x + threadIdx.x) >> 6);
  int lane = threadIdx.x & 63;
  if (gw >= n) return;
  int e0 = rs[gw], e1 = rs[gw + 1];
  int oct = lane >> 3, sub = lane & 7;
  float acc[8] = {};
  int e = e0 + oct;
  for (; e + 8 < e1; e += 16) {
    int a = __builtin_nontemporal_load(csr + e);
    int b = __builtin_nontemporal_load(csr + e + 8);
    half8 va = *(const half8*)&xs[(size_t)a * 64 + 8 * sub];
    half8 vb = *(const half8*)&xs[(size_t)b * 64 + 8 * sub];
#pragma unroll
    for (int j = 0; j < 8; ++j) acc[j] += (float)va[j] + (float)vb[j];
  }
  for (; e < e1; e += 8) {
    int a = __builtin_nontemporal_load(csr + e);
    half8 va = *(const half8*)&xs[(size_t)a * 64 + 8 * sub];
#pragma unroll
    for (int j = 0; j < 8; ++j) acc[j] += (float)va[j];
  }
#pragma unroll
  for (int j = 0; j < 8; ++j) {
    acc[j] += __shfl_xor(acc[j], 32, 64);
    acc[j] += __shfl_xor(acc[j], 16, 64);
    acc[j] += __shfl_xor(acc[j], 8, 64);
  }
  if (oct == 0) {
    float qi = isq[gw];
    half8 self = *(const half8*)&xs[(size_t)gw * 64 + 8 * sub];
#pragma unroll
    for (int j = 0; j < 8; ++j) {
      float r = qi * (acc[j] + (float)self[j]) + bias[8 * sub + j];
      if (RELU) r = fmaxf(r, 0.f);
      out[(size_t)gw * 64 + 8 * sub + j] = r;
    }
  }
}

// ---------------- fused link MLP ----------------

__global__ __launch_bounds__(256) void k_mlp(const float* __restrict__ z,
                                             const int* __restrict__ eli, int nlab,
                                             const float* __restrict__ Wl1,
                                             const float* __restrict__ bl1,
                                             const float* __restrict__ Wl2,
                                             const float* __restrict__ bl2,
                                             float* __restrict__ out) {
  constexpr int K = 128, TM = 4, LDA = K + 4;
  __shared__ float Wl[K * 64];
  __shared__ float Al[64 * LDA];
  int t = threadIdx.x;
  for (int i = t; i < K * 64 / 4; i += 256)
    ((float4*)Wl)[i] = ((const float4*)Wl1)[i];
  int rowbase = blockIdx.x * 64;
  {
    int r = t >> 2, p = t & 3;  // 4 threads/row; p<2 -> z[s], p>=2 -> z[d]
    int row = rowbase + r;
    int idx = 0;
    if (row < nlab) idx = (p < 2) ? eli[row] : eli[nlab + row];
    const float4* src = (const float4*)(z + (size_t)idx * 64);
    int srcq = (p & 1) * 8;
    int dst = r * LDA + (p >= 2 ? 64 : 0) + (p & 1) * 32;
#pragma unroll
    for (int q = 0; q < 8; ++q)
      *(float4*)&Al[dst + 4 * q] = src[srcq + q];
  }
  __syncthreads();
  int tx = t & 15, ty = t >> 4;
  float acc[TM][4] = {};
  for (int k = 0; k < K; ++k) {
    float a[TM];
#pragma unroll
    for (int i = 0; i < TM; ++i) a[i] = Al[(ty * TM + i) * LDA + k];
    float4 w = *(const float4*)&Wl[k * 64 + tx * 4];
#pragma unroll
    for (int i = 0; i < TM; ++i) {
      acc[i][0] += a[i] * w.x;
      acc[i][1] += a[i] * w.y;
      acc[i][2] += a[i] * w.z;
      acc[i][3] += a[i] * w.w;
    }
  }
  float4 b1v = *(const float4*)&bl1[tx * 4];
  float4 w2v = *(const float4*)&Wl2[tx * 4];
  float bias2 = bl2[0];
  float part[TM];
#pragma unroll
  for (int i = 0; i < TM; ++i) {
    float h0 = fmaxf(acc[i][0] + b1v.x, 0.f);
    float h1 = fmaxf(acc[i][1] + b1v.y, 0.f);
    float h2 = fmaxf(acc[i][2] + b1v.z, 0.f);
    float h3 = fmaxf(acc[i][3] + b1v.w, 0.f);
    part[i] = h0 * w2v.x + h1 * w2v.y + h2 * w2v.z + h3 * w2v.w;
  }
#pragma unroll
  for (int i = 0; i < TM; ++i) {
#pragma unroll
    for (int m = 1; m < 16; m <<= 1)
      part[i] += __shfl_xor(part[i], m, 64);
  }
  if (tx == 0) {
#pragma unroll
    for (int i = 0; i < TM; ++i) {
      int row = rowbase + ty * TM + i;
      if (row < nlab) out[row] = part[i] + bias2;
    }
  }
}

// ---------------- launcher ----------------

extern "C" void kernel_launch(void* const* d_in, const int* in_sizes, int n_in,
                              void* d_out, int out_size, void* d_ws, size_t ws_size,
                              hipStream_t stream) {
  const float* x   = (const float*)d_in[0];
  const int*   ei  = (const int*)d_in[1];
  const int*   eli = (const int*)d_in[2];
  const float* W1  = (const float*)d_in[3];
  const float* b1  = (const float*)d_in[4];
  const float* W2  = (const float*)d_in[5];
  const float* b2  = (const float*)d_in[6];
  const float* W3  = (const float*)d_in[7];
  const float* b3  = (const float*)d_in[8];
  const float* Wl1 = (const float*)d_in[9];
  const float* bl1 = (const float*)d_in[10];
  const float* Wl2 = (const float*)d_in[11];
  const float* bl2 = (const float*)d_in[12];
  float* out = (float*)d_out;
  const int n    = in_sizes[0] / 128;
  const int E    = in_sizes[1] / 2;
  const int nlab = in_sizes[2] / 2;
  (void)n_in; (void)out_size; (void)ws_size;

  char* ws = (char*)d_ws;
  size_t off = 0;
  auto alloc = [&](size_t bytes) -> void* {
    void* p = ws + off;
    off = (off + bytes + 255) & ~(size_t)255;
    return p;
  };
  float*     bufZ1 = (float*)alloc((size_t)n * 128 * 4);   // z1 (f32); reused for z3
  float*     bufZ2 = (float*)alloc((size_t)n * 64 * 4);    // z2 (f32)
  _Float16*  bufXS = (_Float16*)alloc((size_t)n * 128 * 2);// xs tables (f16)
  int*       csr   = (int*)alloc((size_t)E * 4);
  unsigned short* rank = (unsigned short*)alloc((size_t)E * 2);
  int*       cnt   = (int*)alloc((size_t)n * 4);
  float*     isq   = (float*)alloc((size_t)n * 4);
  int*       rs    = (int*)alloc((size_t)(n + 1) * 4);
  const int  nb    = (n + 255) / 256;  // 391 blocks
  int*       bsum  = (int*)alloc((size_t)nb * 4);
  _Float16*  Wf1   = (_Float16*)alloc(128 * 128 * 2 * 2);
  _Float16*  Wf2   = (_Float16*)alloc(128 * 64 * 2 * 2);
  _Float16*  Wf3   = (_Float16*)alloc(64 * 64 * 2 * 2);
  float*     z3    = bufZ1;  // reuse (stride 64)

  const int CH  = (E + CHUNK - 1) / CHUNK;  // edge chunks (2048 edges each)
  const int HB  = 8 * CH;                   // role-split hist/fill blocks
  const int GT  = (n + 127) / 128;          // gemm tiles
  const int aggb = (n + 3) / 4;             // 4 waves (nodes) per block

  hipMemsetAsync(cnt, 0, (size_t)n * 4, stream);
  k_hist_wsplit<<<HB + 112, 256, 0, stream>>>(ei, E, n, cnt, rank,
                                              W1, Wf1, W2, Wf2, W3, Wf3, HB);
  k_scan1<<<nb, 256, 0, stream>>>(cnt, bsum, n);
  k_scan23<<<nb, 256, 0, stream>>>(cnt, bsum, nb, rs, isq, n);
  k_fill<<<HB, 256, 0, stream>>>(ei, E, n, rs, rank, csr);

  k_gemm_mfma<128, 128><<<GT, 256, 0, stream>>>(x, Wf1, isq, bufXS, n);
  k_agg128<true><<<aggb, 256, 0, stream>>>(bufXS, rs, csr, isq, b1, bufZ1, n);
  k_gemm_mfma<128, 64><<<GT, 256, 0, stream>>>(bufZ1, Wf2, isq, bufXS, n);
  k_agg64<true><<<aggb, 256, 0, stream>>>(bufXS, rs, csr, isq, b2, bufZ2, n);
  k_gemm_mfma<64, 64><<<GT, 256, 0, stream>>>(bufZ2, Wf3, isq, bufXS, n);
  k_agg64<false><<<aggb, 256, 0, stream>>>(bufXS, rs, csr, isq, b3, z3, n);
  k_mlp<<<(nlab + 63) / 64, 256, 0, stream>>>(z3, eli, nlab, Wl1, bl1, Wl2, bl2, out);
}